// Round 5
// baseline (661.722 us; speedup 1.0000x reference)
//
#include <hip/hip_runtime.h>
#include <stdint.h>

// Problem: B=64, C=512, H=W=32 -> N=65536 pixels, m=512 slots, d=512 dims.
// Inputs f32: query [64][512][32][32], keys [512][512] (selected by size).
// Output **FLOAT32**, concatenated: updated_query [64][1024][32][32] | updated_memory
//   [512][512] | score_query [65536][512] | score_memory [65536][512] | g_loss | s_loss
//
// Pipeline: K0 keys-prep -> K1 norm (q->UQ low half f32 + qb bf16 -> SM-region + sumq)
//   -> K2 score GEMM (raw f32 S -> SQ region, colmax atomics)
//   -> K3 row stats (top2, gidx, s1v, rowinv, loss partials)
//   -> K7 memory update (reads qb -> UM f32)          [qb dies here]
//   -> K4 colsum -> K8 SM = row-softmax(S) f32 (SM region now free)
//   -> K5 SQ = col-softmax in place -> K6 concat GEMM (A = SM f32 -> bf16) -> K9 losses

typedef unsigned int u32;
typedef unsigned long long u64;
typedef unsigned short u16;

typedef float f32x4 __attribute__((ext_vector_type(4)));
typedef short bf16x8 __attribute__((ext_vector_type(8)));

#define DIMS 512

// ---- bf16 helpers (RNE) ----
__device__ __forceinline__ u16 f2bf(float x){
  u32 u = __float_as_uint(x);
  return (u16)((u + 0x7FFFu + ((u >> 16) & 1u)) >> 16);
}
__device__ __forceinline__ float bf2f(u16 h){ return __uint_as_float(((u32)h) << 16); }
__device__ __forceinline__ u32 pack2(float a, float b){
  return (u32)f2bf(a) | ((u32)f2bf(b) << 16);
}
// monotone float<->uint for atomicMax on possibly-negative floats
__device__ __forceinline__ u32 fkey(float x){
  u32 b = __float_as_uint(x);
  return (b & 0x80000000u) ? ~b : (b | 0x80000000u);
}
__device__ __forceinline__ float fdec(u32 u){
  return (u & 0x80000000u) ? __uint_as_float(u & 0x7FFFFFFFu) : __uint_as_float(~u);
}

// ---- K0: keys prep: bf16 copies (normal + transposed), per-slot ||k||^2 and sum(k);
//          zero colmax/colsum (block 0). 512 blocks x 512 threads.
__global__ __launch_bounds__(512) void k0_prep(const float* __restrict__ keys,
    u16* __restrict__ kb, u16* __restrict__ kt,
    float* __restrict__ kn2, float* __restrict__ ksum,
    u32* __restrict__ colmax_u, float* __restrict__ colsum)
{
  const int j = blockIdx.x, t = threadIdx.x;
  float v = keys[(size_t)j * 512 + t];
  u16 h = f2bf(v);
  kb[(size_t)j * 512 + t] = h;
  kt[(size_t)t * 512 + j] = h;
  float s = v, ss = v * v;
  #pragma unroll
  for (int d = 1; d < 64; d <<= 1){ s += __shfl_xor(s, d); ss += __shfl_xor(ss, d); }
  __shared__ float rs[8], rss[8];
  const int w = t >> 6, lane = t & 63;
  if (lane == 0){ rs[w] = s; rss[w] = ss; }
  __syncthreads();
  if (t == 0){
    float S = 0.f, SS = 0.f;
    for (int i = 0; i < 8; ++i){ S += rs[i]; SS += rss[i]; }
    ksum[j] = S; kn2[j] = SS;
  }
  if (j == 0){ colmax_u[t] = 0u; colsum[t] = 0.f; }
}

// ---- K1: channel L2-normalize. Writes q (f32) into updated_query[:, :512] (native layout)
//          and row-major q_bf16 [N][512] (into the SM output region) via LDS transpose,
//          plus per-pixel sum(q). grid (16 p-tiles, 64 b), 256 threads, 64 pixels/block.
__global__ __launch_bounds__(256) void k1_norm(const float* __restrict__ query,
    float* __restrict__ uq, u16* __restrict__ qb, float* __restrict__ sumq)
{
  __shared__ float red[4][64];
  __shared__ float rinvS[64];
  __shared__ float T[64][65];
  const int t = threadIdx.x;
  const int p = t & 63;
  const int cq = t >> 6;           // 0..3
  const int b = blockIdx.y;
  const int p0 = blockIdx.x * 64;
  const float* base = query + (size_t)b * 512 * 1024 + p0;

  float ssq = 0.f;
  for (int c = cq; c < 512; c += 4){
    float v = base[(size_t)c * 1024 + p];
    ssq += v * v;
  }
  red[cq][p] = ssq;
  __syncthreads();
  if (t < 64){
    float tot = red[0][t] + red[1][t] + red[2][t] + red[3][t];
    rinvS[t] = 1.0f / fmaxf(sqrtf(tot), 1e-12f);
  }
  __syncthreads();
  const float rinv = rinvS[p];
  float* uqo = uq + ((size_t)b * 1024) * 1024 + p0;
  float mysum = 0.f;
  const int r = t >> 2, seg = t & 3;
  for (int cb = 0; cb < 8; ++cb){
    #pragma unroll
    for (int i = 0; i < 16; ++i){
      int cc = cq + i * 4;              // 0..63
      int c = cb * 64 + cc;
      float v = base[(size_t)c * 1024 + p] * rinv;
      uqo[(size_t)c * 1024 + p] = v;
      T[cc][p] = v;
      mysum += v;
    }
    __syncthreads();
    {
      u32 wpk[8];
      #pragma unroll
      for (int k = 0; k < 8; ++k)
        wpk[k] = pack2(T[seg * 16 + 2 * k][r], T[seg * 16 + 2 * k + 1][r]);
      uint4* dst = (uint4*)(qb + ((size_t)(b * 1024 + p0 + r)) * 512 + cb * 64 + seg * 16);
      dst[0] = make_uint4(wpk[0], wpk[1], wpk[2], wpk[3]);
      dst[1] = make_uint4(wpk[4], wpk[5], wpk[6], wpk[7]);
    }
    __syncthreads();
  }
  red[cq][p] = mysum;
  __syncthreads();
  if (t < 64)
    sumq[(size_t)b * 1024 + p0 + t] = red[0][t] + red[1][t] + red[2][t] + red[3][t];
}

// ---- K2: score = q @ keys^T (both row-major [*,512] bf16), 128x128 tile, 4 waves 64x64,
// BK=32. Raw f32 scores -> SQ output region; per-column max via atomicMax.
__global__ __launch_bounds__(256) void k2_score(const u16* __restrict__ Aq,
    const u16* __restrict__ Bk, float* __restrict__ Sout, u32* __restrict__ colmax_u)
{
  __shared__ __align__(16) char smem[16384];
  const int t = threadIdx.x;
  const int lane = t & 63;
  const int wid = t >> 6;
  const int l15 = lane & 15, l4 = lane >> 4;
  const int n0 = blockIdx.x * 128;
  const int j0 = blockIdx.y * 128;
  const int wr = (wid & 1) * 64;
  const int wc = (wid >> 1) * 64;
  const int rA = t >> 2;            // 0..63
  const int ch = t & 3;

  f32x4 acc[4][4];
  #pragma unroll
  for (int a = 0; a < 4; ++a)
    #pragma unroll
    for (int b = 0; b < 4; ++b) acc[a][b] = (f32x4){0.f, 0.f, 0.f, 0.f};

  const size_t arow0 = (size_t)(n0 + rA) * DIMS;
  const size_t arow1 = (size_t)(n0 + 64 + rA) * DIMS;
  const size_t brow0 = (size_t)(j0 + rA) * DIMS;
  const size_t brow1 = (size_t)(j0 + 64 + rA) * DIMS;
  const int choff = ch * 8;
  char* As = smem;
  char* Bs = smem + 8192;
  // LDS chunk swizzle sigma(row) = (row>>1)&3 -> 2-way (free) ds_read_b128 conflicts
  const int sw = (ch ^ ((rA >> 1) & 3)) * 16;
  const int dst0 = rA * 64 + sw;
  const int dst1 = (64 + rA) * 64 + sw;   // sigma(row+64) == sigma(row)

  uint4 a0 = *(const uint4*)(Aq + arow0 + choff);
  uint4 a1 = *(const uint4*)(Aq + arow1 + choff);
  uint4 b0 = *(const uint4*)(Bk + brow0 + choff);
  uint4 b1 = *(const uint4*)(Bk + brow1 + choff);

  for (int kk = 0; kk < 16; ++kk){
    __syncthreads();
    *(uint4*)(As + dst0) = a0;
    *(uint4*)(As + dst1) = a1;
    *(uint4*)(Bs + dst0) = b0;
    *(uint4*)(Bs + dst1) = b1;
    __syncthreads();
    if (kk < 15){
      const int ko = (kk + 1) * 32 + choff;
      a0 = *(const uint4*)(Aq + arow0 + ko);
      a1 = *(const uint4*)(Aq + arow1 + ko);
      b0 = *(const uint4*)(Bk + brow0 + ko);
      b1 = *(const uint4*)(Bk + brow1 + ko);
    }
    bf16x8 af[4], bfr[4];
    #pragma unroll
    for (int mi = 0; mi < 4; ++mi){
      int rr = wr + mi * 16 + l15;
      af[mi] = *(const bf16x8*)(As + rr * 64 + ((l4 ^ ((rr >> 1) & 3)) * 16));
    }
    #pragma unroll
    for (int nj = 0; nj < 4; ++nj){
      int rr = wc + nj * 16 + l15;
      bfr[nj] = *(const bf16x8*)(Bs + rr * 64 + ((l4 ^ ((rr >> 1) & 3)) * 16));
    }
    #pragma unroll
    for (int mi = 0; mi < 4; ++mi)
      #pragma unroll
      for (int nj = 0; nj < 4; ++nj)
        acc[mi][nj] = __builtin_amdgcn_mfma_f32_16x16x32_bf16(af[mi], bfr[nj], acc[mi][nj], 0, 0, 0);
  }

  // epilogue: direct f32 stores (row = n0+wr+mi*16+l4*4+e, col = j0+wc+nj*16+l15)
  #pragma unroll
  for (int nj = 0; nj < 4; ++nj){
    float cmax = -3.0e38f;
    const int col = j0 + wc + nj * 16 + l15;
    #pragma unroll
    for (int mi = 0; mi < 4; ++mi){
      #pragma unroll
      for (int e = 0; e < 4; ++e){
        float v = acc[mi][nj][e];
        Sout[(size_t)(n0 + wr + mi * 16 + l4 * 4 + e) * 512 + col] = v;
        cmax = fmaxf(cmax, v);
      }
    }
    cmax = fmaxf(cmax, __shfl_xor(cmax, 16));
    cmax = fmaxf(cmax, __shfl_xor(cmax, 32));
    if (l4 == 0) atomicMax(&colmax_u[col], fkey(cmax));
  }
}

// ---- K3: per-row stats from raw f32 S: top2 -> gidx,s1v ; row softmax denom -> rowinv ;
// losses via ||q-k||^2 = 1 + ||k||^2 - 2 s (eps folds to 2e-6*(sum q - sum k)+512e-12).
__global__ __launch_bounds__(256) void k3_row(const float* __restrict__ S,
    int* __restrict__ gidx, float* __restrict__ s1v, float* __restrict__ rowinv,
    const float* __restrict__ kn2, const float* __restrict__ ksum,
    const float* __restrict__ sumq, float* __restrict__ part)
{
  const int t = threadIdx.x;
  const int lane = t & 63;
  const int w = t >> 6;
  const int n = blockIdx.x * 4 + w;
  const float* row = S + (size_t)n * 512 + lane * 8;
  float4 r0 = *(const float4*)(row);
  float4 r1 = *(const float4*)(row + 4);
  float v[8] = {r0.x, r0.y, r0.z, r0.w, r1.x, r1.y, r1.z, r1.w};

  float m1 = -3e38f, m2 = -3e38f; int i1 = 0x7FFFFFFF, i2 = 0x7FFFFFFF;
  #pragma unroll
  for (int k = 0; k < 8; ++k){
    int idx = lane * 8 + k; float val = v[k];
    if (val > m1 || (val == m1 && idx < i1)){ m2 = m1; i2 = i1; m1 = val; i1 = idx; }
    else if (val > m2 || (val == m2 && idx < i2)){ m2 = val; i2 = idx; }
  }
  #pragma unroll
  for (int d = 1; d < 64; d <<= 1){
    float o1 = __shfl_xor(m1, d), o2 = __shfl_xor(m2, d);
    int oi1 = __shfl_xor(i1, d), oi2 = __shfl_xor(i2, d);
    if (o1 > m1 || (o1 == m1 && oi1 < i1)){
      if (m1 > o2 || (m1 == o2 && i1 < oi2)){ m2 = m1; i2 = i1; }
      else { m2 = o2; i2 = oi2; }
      m1 = o1; i1 = oi1;
    } else {
      if (o1 > m2 || (o1 == m2 && oi1 < i2)){ m2 = o1; i2 = oi1; }
    }
  }
  float es = 0.f;
  #pragma unroll
  for (int k = 0; k < 8; ++k) es += expf(v[k] - m1);
  #pragma unroll
  for (int d = 1; d < 64; d <<= 1) es += __shfl_xor(es, d);

  __shared__ float gred[4], sred[4];
  if (lane == 0){
    gidx[n] = i1; s1v[n] = m1; rowinv[n] = 1.0f / es;
    float sq = sumq[n];
    float gl = 1.0f + kn2[i1] - 2.0f * m1;                      // ||q - k_top1||^2
    float dp2 = gl + 2e-6f * (sq - ksum[i1]) + 5.12e-10f;
    float dn2 = 1.0f + kn2[i2] - 2.0f * m2 + 2e-6f * (sq - ksum[i2]) + 5.12e-10f;
    float sl = fmaxf(sqrtf(dp2) - sqrtf(dn2) + 1.0f, 0.0f);
    gred[w] = gl; sred[w] = sl;
  }
  __syncthreads();
  if (t == 0){
    part[2 * (size_t)blockIdx.x]     = gred[0] + gred[1] + gred[2] + gred[3];
    part[2 * (size_t)blockIdx.x + 1] = sred[0] + sred[1] + sred[2] + sred[3];
  }
}

// ---- K7: memory update. One block per slot j: ballot-scan gidx, accumulate
// wgt_n * q_n (wgt = exp(s1 - colmax[g]) == score_query[n,g]/col_max), add keys row,
// L2-normalize, write f32. Last consumer of qb.
__global__ __launch_bounds__(256) void k7_update(const int* __restrict__ gidx,
    const float* __restrict__ s1v, const u32* __restrict__ colmax_u,
    const u16* __restrict__ qb, const float* __restrict__ keys, float* __restrict__ um)
{
  const int j = blockIdx.x;
  const int t = threadIdx.x;
  const int lane = t & 63;
  const int w = t >> 6;
  const float cm = fdec(colmax_u[j]);
  float acc[8] = {0.f, 0.f, 0.f, 0.f, 0.f, 0.f, 0.f, 0.f};
  const int b0 = w * 16384, b1 = b0 + 16384;
  for (int base = b0; base < b1; base += 64){
    u64 mask = __ballot(gidx[base + lane] == j);
    while (mask){
      int bpos = (int)__builtin_ctzll(mask);
      mask &= mask - 1;
      int rrow = base + bpos;
      float wgt = expf(s1v[rrow] - cm);
      uint4 rv = *(const uint4*)(qb + (size_t)rrow * 512 + lane * 8);
      u32 a4[4] = {rv.x, rv.y, rv.z, rv.w};
      #pragma unroll
      for (int q = 0; q < 4; ++q){
        acc[2 * q]     += wgt * bf2f((u16)(a4[q] & 0xFFFFu));
        acc[2 * q + 1] += wgt * bf2f((u16)(a4[q] >> 16));
      }
    }
  }
  __shared__ float red[512];
  for (int i = t; i < 512; i += 256) red[i] = 0.f;
  __syncthreads();
  #pragma unroll
  for (int k = 0; k < 8; ++k) atomicAdd(&red[lane * 8 + k], acc[k]);
  __syncthreads();
  float v0 = red[t]       + keys[(size_t)j * 512 + t];
  float v1 = red[t + 256] + keys[(size_t)j * 512 + t + 256];
  float ssq = v0 * v0 + v1 * v1;
  #pragma unroll
  for (int d = 1; d < 64; d <<= 1) ssq += __shfl_xor(ssq, d);
  __shared__ float rr4[4];
  if (lane == 0) rr4[w] = ssq;
  __syncthreads();
  const float rinv = 1.0f / fmaxf(sqrtf(rr4[0] + rr4[1] + rr4[2] + rr4[3]), 1e-12f);
  um[(size_t)j * 512 + t]       = v0 * rinv;
  um[(size_t)j * 512 + t + 256] = v1 * rinv;
}

// ---- K4: column softmax denominators from raw f32 S. 512 blocks x 128 rows.
__global__ __launch_bounds__(256) void k4_colsum(const float* __restrict__ S,
    const u32* __restrict__ colmax_u, float* __restrict__ colsum)
{
  const int t = threadIdx.x;
  const int n0 = blockIdx.x * 128;
  const float cm0 = fdec(colmax_u[t]);
  const float cm1 = fdec(colmax_u[t + 256]);
  float s0 = 0.f, s1 = 0.f;
  for (int rr = 0; rr < 128; ++rr){
    const float* row = S + (size_t)(n0 + rr) * 512;
    s0 += expf(row[t] - cm0);
    s1 += expf(row[t + 256] - cm1);
  }
  atomicAdd(&colsum[t], s0);
  atomicAdd(&colsum[t + 256], s1);
}

// ---- K8: score_memory = exp(s - rowmax) * rowinv (row softmax of raw f32 S) -> SM region
// (free after K7). MUST run before K5 (which destroys raw S).
__global__ __launch_bounds__(256) void k8_smw(const float* __restrict__ S,
    const float* __restrict__ s1v, const float* __restrict__ rowinv, float* __restrict__ SM)
{
  const size_t i = ((size_t)blockIdx.x * 256 + threadIdx.x) * 8;
  const int n = (int)(i >> 9);
  const float m1 = s1v[n], inv = rowinv[n];
  float4 r0 = *(const float4*)(S + i);
  float4 r1 = *(const float4*)(S + i + 4);
  float4 o0, o1;
  o0.x = expf(r0.x - m1) * inv; o0.y = expf(r0.y - m1) * inv;
  o0.z = expf(r0.z - m1) * inv; o0.w = expf(r0.w - m1) * inv;
  o1.x = expf(r1.x - m1) * inv; o1.y = expf(r1.y - m1) * inv;
  o1.z = expf(r1.z - m1) * inv; o1.w = expf(r1.w - m1) * inv;
  *(float4*)(SM + i) = o0;
  *(float4*)(SM + i + 4) = o1;
}

// ---- K5: score_query = exp(s - colmax)/colsum, in place over raw f32 scores.
__global__ __launch_bounds__(256) void k5_sq(float* __restrict__ S,
    const u32* __restrict__ colmax_u, const float* __restrict__ colsum)
{
  const size_t i = ((size_t)blockIdx.x * 256 + threadIdx.x) * 8;
  const int c = (int)(i & 511);
  float4 r0 = *(const float4*)(S + i);
  float4 r1 = *(const float4*)(S + i + 4);
  float o[8] = {r0.x, r0.y, r0.z, r0.w, r1.x, r1.y, r1.z, r1.w};
  #pragma unroll
  for (int k = 0; k < 8; ++k)
    o[k] = expf(o[k] - fdec(colmax_u[c + k])) / colsum[c + k];
  *(float4*)(S + i)     = (float4){o[0], o[1], o[2], o[3]};
  *(float4*)(S + i + 4) = (float4){o[4], o[5], o[6], o[7]};
}

// ---- K6: concat = score_memory @ keys -> updated_query[:, 512:] (f32, strided channels).
// A operand: f32 SM converted to bf16 during staging. B operand: kt (keys^T) bf16.
__global__ __launch_bounds__(256) void k6_concat(const float* __restrict__ Ap,
    const u16* __restrict__ BkT, float* __restrict__ Uq)
{
  __shared__ __align__(16) char smem[16384];
  const int t = threadIdx.x;
  const int lane = t & 63;
  const int wid = t >> 6;
  const int l15 = lane & 15, l4 = lane >> 4;
  const int n0 = blockIdx.x * 128;
  const int j0 = blockIdx.y * 128;     // output channel block
  const int wr = (wid & 1) * 64;
  const int wc = (wid >> 1) * 64;
  const int rA = t >> 2;
  const int ch = t & 3;

  f32x4 acc[4][4];
  #pragma unroll
  for (int a = 0; a < 4; ++a)
    #pragma unroll
    for (int b = 0; b < 4; ++b) acc[a][b] = (f32x4){0.f, 0.f, 0.f, 0.f};

  const size_t arow0 = (size_t)(n0 + rA) * DIMS;
  const size_t arow1 = (size_t)(n0 + 64 + rA) * DIMS;
  const size_t brow0 = (size_t)(j0 + rA) * DIMS;
  const size_t brow1 = (size_t)(j0 + 64 + rA) * DIMS;
  const int choff = ch * 8;
  char* As = smem;
  char* Bs = smem + 8192;
  const int sw = (ch ^ ((rA >> 1) & 3)) * 16;
  const int dst0 = rA * 64 + sw;
  const int dst1 = (64 + rA) * 64 + sw;

  float4 fa00 = *(const float4*)(Ap + arow0 + choff);
  float4 fa01 = *(const float4*)(Ap + arow0 + choff + 4);
  float4 fa10 = *(const float4*)(Ap + arow1 + choff);
  float4 fa11 = *(const float4*)(Ap + arow1 + choff + 4);
  uint4 b0 = *(const uint4*)(BkT + brow0 + choff);
  uint4 b1 = *(const uint4*)(BkT + brow1 + choff);

  for (int kk = 0; kk < 16; ++kk){
    uint4 a0 = make_uint4(pack2(fa00.x, fa00.y), pack2(fa00.z, fa00.w),
                          pack2(fa01.x, fa01.y), pack2(fa01.z, fa01.w));
    uint4 a1 = make_uint4(pack2(fa10.x, fa10.y), pack2(fa10.z, fa10.w),
                          pack2(fa11.x, fa11.y), pack2(fa11.z, fa11.w));
    __syncthreads();
    *(uint4*)(As + dst0) = a0;
    *(uint4*)(As + dst1) = a1;
    *(uint4*)(Bs + dst0) = b0;
    *(uint4*)(Bs + dst1) = b1;
    __syncthreads();
    if (kk < 15){
      const int ko = (kk + 1) * 32 + choff;
      fa00 = *(const float4*)(Ap + arow0 + ko);
      fa01 = *(const float4*)(Ap + arow0 + ko + 4);
      fa10 = *(const float4*)(Ap + arow1 + ko);
      fa11 = *(const float4*)(Ap + arow1 + ko + 4);
      b0 = *(const uint4*)(BkT + brow0 + ko);
      b1 = *(const uint4*)(BkT + brow1 + ko);
    }
    bf16x8 af[4], bfr[4];
    #pragma unroll
    for (int mi = 0; mi < 4; ++mi){
      int rr = wr + mi * 16 + l15;
      af[mi] = *(const bf16x8*)(As + rr * 64 + ((l4 ^ ((rr >> 1) & 3)) * 16));
    }
    #pragma unroll
    for (int nj = 0; nj < 4; ++nj){
      int rr = wc + nj * 16 + l15;
      bfr[nj] = *(const bf16x8*)(Bs + rr * 64 + ((l4 ^ ((rr >> 1) & 3)) * 16));
    }
    #pragma unroll
    for (int mi = 0; mi < 4; ++mi)
      #pragma unroll
      for (int nj = 0; nj < 4; ++nj)
        acc[mi][nj] = __builtin_amdgcn_mfma_f32_16x16x32_bf16(af[mi], bfr[nj], acc[mi][nj], 0, 0, 0);
  }

  // epilogue: acc e-index = consecutive tile rows = consecutive pixels -> float4 stores.
  const int bq = n0 >> 10;
  const int p0 = n0 & 1023;
  #pragma unroll
  for (int nj = 0; nj < 4; ++nj){
    const size_t chn = (size_t)(bq * 1024 + 512 + j0 + wc + nj * 16 + l15) * 1024;
    #pragma unroll
    for (int mi = 0; mi < 4; ++mi){
      f32x4 v = acc[mi][nj];
      *(float4*)(Uq + chn + p0 + wr + mi * 16 + l4 * 4) = (float4){v[0], v[1], v[2], v[3]};
    }
  }
}

// ---- K9: reduce per-block loss partials -> scalar f32 outputs.
__global__ __launch_bounds__(256) void k9_fin(const float* __restrict__ part,
    float* __restrict__ outL)
{
  const int t = threadIdx.x;
  float gs = 0.f, ss = 0.f;
  for (int i = t; i < 16384; i += 256){ gs += part[2 * i]; ss += part[2 * i + 1]; }
  #pragma unroll
  for (int d = 1; d < 64; d <<= 1){ gs += __shfl_xor(gs, d); ss += __shfl_xor(ss, d); }
  __shared__ float rg[4], rs2[4];
  if ((t & 63) == 0){ rg[t >> 6] = gs; rs2[t >> 6] = ss; }
  __syncthreads();
  if (t == 0){
    float G = rg[0] + rg[1] + rg[2] + rg[3];
    float S = rs2[0] + rs2[1] + rs2[2] + rs2[3];
    outL[0] = G / (65536.0f * 512.0f);
    outL[1] = S / 65536.0f;
  }
}

extern "C" void kernel_launch(void* const* d_in, const int* in_sizes, int n_in,
                              void* d_out, int out_size, void* d_ws, size_t ws_size,
                              hipStream_t stream)
{
  // query = 33,554,432-element tensor, keys = 262,144, regardless of ordering.
  int qi = 0, ki = 1;
  if (n_in >= 2 && in_sizes[0] < in_sizes[1]){ qi = 1; ki = 0; }
  const float* query = (const float*)d_in[qi];
  const float* keys  = (const float*)d_in[ki];
  float* out = (float*)d_out;

  // output offsets (f32 elements)
  const size_t OFF_UQ = 0;
  const size_t OFF_UM = 67108864;
  const size_t OFF_SQ = 67371008;
  const size_t OFF_SM = 100925440;
  const size_t OFF_GL = 134479872;

  // q_bf16 [N][512] parked in the first half of the score_memory f32 region until K7.
  u16* qb = (u16*)(out + OFF_SM);

  // workspace layout (~2.24 MB total)
  char* ws = (char*)d_ws;
  u16*   kb     = (u16*)ws;                       //   524,288 B
  u16*   kt     = (u16*)(ws + 524288);            //   524,288
  float* sumq   = (float*)(ws + 1048576);         //   262,144
  int*   gidx   = (int*)(ws + 1310720);           //   262,144
  float* s1v    = (float*)(ws + 1572864);         //   262,144
  float* rowinv = (float*)(ws + 1835008);         //   262,144
  float* part   = (float*)(ws + 2097152);         //   131,072
  float* kn2    = (float*)(ws + 2228224);         //     2,048
  float* ksum   = (float*)(ws + 2230272);         //     2,048
  u32*   colmax = (u32*)(ws + 2232320);           //     2,048
  float* colsum = (float*)(ws + 2234368);         //     2,048

  k0_prep<<<512, 512, 0, stream>>>(keys, kb, kt, kn2, ksum, colmax, colsum);
  k1_norm<<<dim3(16, 64), 256, 0, stream>>>(query, out + OFF_UQ, qb, sumq);
  k2_score<<<dim3(512, 4), 256, 0, stream>>>(qb, kb, out + OFF_SQ, colmax);
  k3_row<<<16384, 256, 0, stream>>>(out + OFF_SQ, gidx, s1v, rowinv, kn2, ksum, sumq, part);
  k7_update<<<512, 256, 0, stream>>>(gidx, s1v, colmax, qb, keys, out + OFF_UM);
  k4_colsum<<<512, 256, 0, stream>>>(out + OFF_SQ, colmax, colsum);
  k8_smw<<<16384, 256, 0, stream>>>(out + OFF_SQ, s1v, rowinv, out + OFF_SM);
  k5_sq<<<16384, 256, 0, stream>>>(out + OFF_SQ, colmax, colsum);
  k6_concat<<<dim3(512, 4), 256, 0, stream>>>(out + OFF_SM, kt, out + OFF_UQ);
  k9_fin<<<1, 256, 0, stream>>>(part, out + OFF_GL);
}

// Round 6
// 553.203 us; speedup vs baseline: 1.1962x; 1.1962x over previous
//
#include <hip/hip_runtime.h>
#include <stdint.h>

// Problem: B=64, C=512, H=W=32 -> N=65536 pixels, m=512 slots, d=512 dims.
// Inputs f32: query [64][512][32][32], keys [512][512] (selected by size).
// Output FLOAT32, concatenated: updated_query [64][1024][32][32] | updated_memory
//   [512][512] | score_query [65536][512] | score_memory [65536][512] | g_loss | s_loss
//
// R6 pipeline (8 kernels, ~1.41 GB HBM traffic):
//   K0 keys-prep (kb, kt, ||k||^2, sum k, zero colmax/colsum)
//   K1 norm: single pass (regs), q->UQ low half f32, qb bf16 -> SM-region-half, sumq
//   K2 score GEMM: raw f32 S -> PARKED in UQ-high slabs; colmax + colsum(=sum exp s,
//      no max subtraction: |s|<~6 so exp bounded) atomics
//   K3 row stats: top2 -> gidx,s1v ; rowsum -> rowinv ; loss partials (reads parked S)
//   K7 memory update (reads qb from SM region; writes UM)        [qb dies here]
//   K58 fused: one read of parked S -> SM = exp(s-m1)*rowinv AND SQ = exp(s)/colsum
//      (SM write destroys qb; SQ region written exactly once)
//   K6 concat GEMM: SM @ keys -> UQ high channels (overwrites parked S, already dead)
//   K9 loss reduce.

typedef unsigned int u32;
typedef unsigned long long u64;
typedef unsigned short u16;

typedef float f32x4 __attribute__((ext_vector_type(4)));
typedef short bf16x8 __attribute__((ext_vector_type(8)));

#define DIMS 512

// ---- bf16 helpers (RNE) ----
__device__ __forceinline__ u16 f2bf(float x){
  u32 u = __float_as_uint(x);
  return (u16)((u + 0x7FFFu + ((u >> 16) & 1u)) >> 16);
}
__device__ __forceinline__ float bf2f(u16 h){ return __uint_as_float(((u32)h) << 16); }
__device__ __forceinline__ u32 pack2(float a, float b){
  return (u32)f2bf(a) | ((u32)f2bf(b) << 16);
}
// monotone float<->uint for atomicMax on possibly-negative floats
__device__ __forceinline__ u32 fkey(float x){
  u32 b = __float_as_uint(x);
  return (b & 0x80000000u) ? ~b : (b | 0x80000000u);
}
__device__ __forceinline__ float fdec(u32 u){
  return (u & 0x80000000u) ? __uint_as_float(u & 0x7FFFFFFFu) : __uint_as_float(~u);
}
// parked raw-S addressing inside the UQ-high region (f32 elements):
__device__ __forceinline__ size_t spark_row(int n){
  return (size_t)(n >> 10) * 1048576 + 524288 + (size_t)(n & 1023) * 512;
}

// ---- K0: keys prep. 512 blocks x 512 threads.
__global__ __launch_bounds__(512) void k0_prep(const float* __restrict__ keys,
    u16* __restrict__ kb, u16* __restrict__ kt,
    float* __restrict__ kn2, float* __restrict__ ksum,
    u32* __restrict__ colmax_u, float* __restrict__ colsum)
{
  const int j = blockIdx.x, t = threadIdx.x;
  float v = keys[(size_t)j * 512 + t];
  u16 h = f2bf(v);
  kb[(size_t)j * 512 + t] = h;
  kt[(size_t)t * 512 + j] = h;
  float s = v, ss = v * v;
  #pragma unroll
  for (int d = 1; d < 64; d <<= 1){ s += __shfl_xor(s, d); ss += __shfl_xor(ss, d); }
  __shared__ float rs[8], rss[8];
  const int w = t >> 6, lane = t & 63;
  if (lane == 0){ rs[w] = s; rss[w] = ss; }
  __syncthreads();
  if (t == 0){
    float S = 0.f, SS = 0.f;
    for (int i = 0; i < 8; ++i){ S += rs[i]; SS += rss[i]; }
    ksum[j] = S; kn2[j] = SS;
  }
  if (j == 0){ colmax_u[t] = 0u; colsum[t] = 0.f; }
}

// ---- K1: channel L2-normalize, single global pass (values held in 128 regs/thread).
// Writes q f32 into UQ[:, :512], q bf16 row-major [N][512] into the SM-region half,
// and per-pixel sum(q). grid (16 p-tiles, 64 b), 256 threads, 64 pixels/block.
__global__ __launch_bounds__(256) void k1_norm(const float* __restrict__ query,
    float* __restrict__ uq, u16* __restrict__ qb, float* __restrict__ sumq)
{
  __shared__ float red[4][64];
  __shared__ float rinvS[64];
  __shared__ float T[64][65];
  const int t = threadIdx.x;
  const int p = t & 63;
  const int cq = t >> 6;           // 0..3
  const int b = blockIdx.y;
  const int p0 = blockIdx.x * 64;
  const float* base = query + (size_t)b * 524288 + p0;

  float v[128];
  float ssq = 0.f;
  #pragma unroll
  for (int k = 0; k < 128; ++k){
    float x = base[(size_t)(cq + 4 * k) * 1024 + p];
    v[k] = x; ssq += x * x;
  }
  red[cq][p] = ssq;
  __syncthreads();
  if (t < 64){
    float tot = red[0][t] + red[1][t] + red[2][t] + red[3][t];
    rinvS[t] = 1.0f / fmaxf(sqrtf(tot), 1e-12f);
  }
  __syncthreads();
  const float rinv = rinvS[p];
  float* uqo = uq + (size_t)b * 1048576 + p0;
  float mysum = 0.f;
  const int r = t >> 2, seg = t & 3;
  for (int cb = 0; cb < 8; ++cb){
    #pragma unroll
    for (int i = 0; i < 16; ++i){
      int c = cb * 64 + cq + i * 4;
      float x = v[cb * 16 + i] * rinv;
      uqo[(size_t)c * 1024 + p] = x;
      T[cq + i * 4][p] = x;
      mysum += x;
    }
    __syncthreads();
    {
      u32 wpk[8];
      #pragma unroll
      for (int k = 0; k < 8; ++k)
        wpk[k] = pack2(T[seg * 16 + 2 * k][r], T[seg * 16 + 2 * k + 1][r]);
      uint4* dst = (uint4*)(qb + ((size_t)(b * 1024 + p0 + r)) * 512 + cb * 64 + seg * 16);
      dst[0] = make_uint4(wpk[0], wpk[1], wpk[2], wpk[3]);
      dst[1] = make_uint4(wpk[4], wpk[5], wpk[6], wpk[7]);
    }
    __syncthreads();
  }
  red[cq][p] = mysum;
  __syncthreads();
  if (t < 64)
    sumq[(size_t)b * 1024 + p0 + t] = red[0][t] + red[1][t] + red[2][t] + red[3][t];
}

// ---- K2: score = q @ keys^T, 128x128 tile, 4 waves 64x64, BK=32. Raw f32 scores
// parked in UQ-high slabs; per-column max AND per-column sum(exp(s)) via atomics.
__global__ __launch_bounds__(256) void k2_score(const u16* __restrict__ Aq,
    const u16* __restrict__ Bk, float* __restrict__ UqBase,
    u32* __restrict__ colmax_u, float* __restrict__ colsum)
{
  __shared__ __align__(16) char smem[16384];
  const int t = threadIdx.x;
  const int lane = t & 63;
  const int wid = t >> 6;
  const int l15 = lane & 15, l4 = lane >> 4;
  const int n0 = blockIdx.x * 128;
  const int j0 = blockIdx.y * 128;
  const int wr = (wid & 1) * 64;
  const int wc = (wid >> 1) * 64;
  const int rA = t >> 2;            // 0..63
  const int ch = t & 3;

  f32x4 acc[4][4];
  #pragma unroll
  for (int a = 0; a < 4; ++a)
    #pragma unroll
    for (int b = 0; b < 4; ++b) acc[a][b] = (f32x4){0.f, 0.f, 0.f, 0.f};

  const size_t arow0 = (size_t)(n0 + rA) * DIMS;
  const size_t arow1 = (size_t)(n0 + 64 + rA) * DIMS;
  const size_t brow0 = (size_t)(j0 + rA) * DIMS;
  const size_t brow1 = (size_t)(j0 + 64 + rA) * DIMS;
  const int choff = ch * 8;
  char* As = smem;
  char* Bs = smem + 8192;
  const int sw = (ch ^ ((rA >> 1) & 3)) * 16;
  const int dst0 = rA * 64 + sw;
  const int dst1 = (64 + rA) * 64 + sw;

  uint4 a0 = *(const uint4*)(Aq + arow0 + choff);
  uint4 a1 = *(const uint4*)(Aq + arow1 + choff);
  uint4 b0 = *(const uint4*)(Bk + brow0 + choff);
  uint4 b1 = *(const uint4*)(Bk + brow1 + choff);

  for (int kk = 0; kk < 16; ++kk){
    __syncthreads();
    *(uint4*)(As + dst0) = a0;
    *(uint4*)(As + dst1) = a1;
    *(uint4*)(Bs + dst0) = b0;
    *(uint4*)(Bs + dst1) = b1;
    __syncthreads();
    if (kk < 15){
      const int ko = (kk + 1) * 32 + choff;
      a0 = *(const uint4*)(Aq + arow0 + ko);
      a1 = *(const uint4*)(Aq + arow1 + ko);
      b0 = *(const uint4*)(Bk + brow0 + ko);
      b1 = *(const uint4*)(Bk + brow1 + ko);
    }
    bf16x8 af[4], bfr[4];
    #pragma unroll
    for (int mi = 0; mi < 4; ++mi){
      int rr = wr + mi * 16 + l15;
      af[mi] = *(const bf16x8*)(As + rr * 64 + ((l4 ^ ((rr >> 1) & 3)) * 16));
    }
    #pragma unroll
    for (int nj = 0; nj < 4; ++nj){
      int rr = wc + nj * 16 + l15;
      bfr[nj] = *(const bf16x8*)(Bs + rr * 64 + ((l4 ^ ((rr >> 1) & 3)) * 16));
    }
    #pragma unroll
    for (int mi = 0; mi < 4; ++mi)
      #pragma unroll
      for (int nj = 0; nj < 4; ++nj)
        acc[mi][nj] = __builtin_amdgcn_mfma_f32_16x16x32_bf16(af[mi], bfr[nj], acc[mi][nj], 0, 0, 0);
  }

  // epilogue: parked f32 stores + per-column max and exp-sum atomics
  float* Sp = UqBase + spark_row(n0);
  #pragma unroll
  for (int nj = 0; nj < 4; ++nj){
    float cmax = -3.0e38f;
    float csum = 0.f;
    const int col = j0 + wc + nj * 16 + l15;
    #pragma unroll
    for (int mi = 0; mi < 4; ++mi){
      #pragma unroll
      for (int e = 0; e < 4; ++e){
        float vv = acc[mi][nj][e];
        Sp[(size_t)(wr + mi * 16 + l4 * 4 + e) * 512 + col] = vv;
        cmax = fmaxf(cmax, vv);
        csum += expf(vv);
      }
    }
    cmax = fmaxf(cmax, __shfl_xor(cmax, 16));
    cmax = fmaxf(cmax, __shfl_xor(cmax, 32));
    csum += __shfl_xor(csum, 16);
    csum += __shfl_xor(csum, 32);
    if (l4 == 0){
      atomicMax(&colmax_u[col], fkey(cmax));
      atomicAdd(&colsum[col], csum);
    }
  }
}

// ---- K3: per-row stats from parked f32 S: top2 -> gidx,s1v ; rowsum -> rowinv ;
// losses via ||q-k||^2 = 1 + ||k||^2 - 2 s (eps folds to 2e-6*(sum q - sum k)+512e-12).
__global__ __launch_bounds__(256) void k3_row(const float* __restrict__ UqBase,
    int* __restrict__ gidx, float* __restrict__ s1v, float* __restrict__ rowinv,
    const float* __restrict__ kn2, const float* __restrict__ ksum,
    const float* __restrict__ sumq, float* __restrict__ part)
{
  const int t = threadIdx.x;
  const int lane = t & 63;
  const int w = t >> 6;
  const int n = blockIdx.x * 4 + w;
  const float* row = UqBase + spark_row(n) + lane * 8;
  float4 r0 = *(const float4*)(row);
  float4 r1 = *(const float4*)(row + 4);
  float v[8] = {r0.x, r0.y, r0.z, r0.w, r1.x, r1.y, r1.z, r1.w};

  float m1 = -3e38f, m2 = -3e38f; int i1 = 0x7FFFFFFF, i2 = 0x7FFFFFFF;
  #pragma unroll
  for (int k = 0; k < 8; ++k){
    int idx = lane * 8 + k; float val = v[k];
    if (val > m1 || (val == m1 && idx < i1)){ m2 = m1; i2 = i1; m1 = val; i1 = idx; }
    else if (val > m2 || (val == m2 && idx < i2)){ m2 = val; i2 = idx; }
  }
  #pragma unroll
  for (int d = 1; d < 64; d <<= 1){
    float o1 = __shfl_xor(m1, d), o2 = __shfl_xor(m2, d);
    int oi1 = __shfl_xor(i1, d), oi2 = __shfl_xor(i2, d);
    if (o1 > m1 || (o1 == m1 && oi1 < i1)){
      if (m1 > o2 || (m1 == o2 && i1 < oi2)){ m2 = m1; i2 = i1; }
      else { m2 = o2; i2 = oi2; }
      m1 = o1; i1 = oi1;
    } else {
      if (o1 > m2 || (o1 == m2 && oi1 < i2)){ m2 = o1; i2 = oi1; }
    }
  }
  float es = 0.f;
  #pragma unroll
  for (int k = 0; k < 8; ++k) es += expf(v[k] - m1);
  #pragma unroll
  for (int d = 1; d < 64; d <<= 1) es += __shfl_xor(es, d);

  __shared__ float gred[4], sred[4];
  if (lane == 0){
    gidx[n] = i1; s1v[n] = m1; rowinv[n] = 1.0f / es;
    float sq = sumq[n];
    float gl = 1.0f + kn2[i1] - 2.0f * m1;                      // ||q - k_top1||^2
    float dp2 = gl + 2e-6f * (sq - ksum[i1]) + 5.12e-10f;
    float dn2 = 1.0f + kn2[i2] - 2.0f * m2 + 2e-6f * (sq - ksum[i2]) + 5.12e-10f;
    float sl = fmaxf(sqrtf(dp2) - sqrtf(dn2) + 1.0f, 0.0f);
    gred[w] = gl; sred[w] = sl;
  }
  __syncthreads();
  if (t == 0){
    part[2 * (size_t)blockIdx.x]     = gred[0] + gred[1] + gred[2] + gred[3];
    part[2 * (size_t)blockIdx.x + 1] = sred[0] + sred[1] + sred[2] + sred[3];
  }
}

// ---- K7: memory update. One block per slot j; wgt = exp(s1 - colmax[g]). Reads qb.
__global__ __launch_bounds__(256) void k7_update(const int* __restrict__ gidx,
    const float* __restrict__ s1v, const u32* __restrict__ colmax_u,
    const u16* __restrict__ qb, const float* __restrict__ keys, float* __restrict__ um)
{
  const int j = blockIdx.x;
  const int t = threadIdx.x;
  const int lane = t & 63;
  const int w = t >> 6;
  const float cm = fdec(colmax_u[j]);
  float acc[8] = {0.f, 0.f, 0.f, 0.f, 0.f, 0.f, 0.f, 0.f};
  const int b0 = w * 16384, b1 = b0 + 16384;
  for (int base = b0; base < b1; base += 64){
    u64 mask = __ballot(gidx[base + lane] == j);
    while (mask){
      int bpos = (int)__builtin_ctzll(mask);
      mask &= mask - 1;
      int rrow = base + bpos;
      float wgt = expf(s1v[rrow] - cm);
      uint4 rv = *(const uint4*)(qb + (size_t)rrow * 512 + lane * 8);
      u32 a4[4] = {rv.x, rv.y, rv.z, rv.w};
      #pragma unroll
      for (int q = 0; q < 4; ++q){
        acc[2 * q]     += wgt * bf2f((u16)(a4[q] & 0xFFFFu));
        acc[2 * q + 1] += wgt * bf2f((u16)(a4[q] >> 16));
      }
    }
  }
  __shared__ float red[512];
  for (int i = t; i < 512; i += 256) red[i] = 0.f;
  __syncthreads();
  #pragma unroll
  for (int k = 0; k < 8; ++k) atomicAdd(&red[lane * 8 + k], acc[k]);
  __syncthreads();
  float v0 = red[t]       + keys[(size_t)j * 512 + t];
  float v1 = red[t + 256] + keys[(size_t)j * 512 + t + 256];
  float ssq = v0 * v0 + v1 * v1;
  #pragma unroll
  for (int d = 1; d < 64; d <<= 1) ssq += __shfl_xor(ssq, d);
  __shared__ float rr4[4];
  if (lane == 0) rr4[w] = ssq;
  __syncthreads();
  const float rinv = 1.0f / fmaxf(sqrtf(rr4[0] + rr4[1] + rr4[2] + rr4[3]), 1e-12f);
  um[(size_t)j * 512 + t]       = v0 * rinv;
  um[(size_t)j * 512 + t + 256] = v1 * rinv;
}

// ---- K58: one read of parked S -> SM = exp(s-m1)*rowinv AND SQ = exp(s)/colsum.
// SQ written as exp(s-m1)*exp(m1)/colsum (identical math, one exp per element).
__global__ __launch_bounds__(256) void k58_smsq(const float* __restrict__ UqBase,
    const float* __restrict__ s1v, const float* __restrict__ rowinv,
    const float* __restrict__ colsum, float* __restrict__ SM, float* __restrict__ SQ)
{
  const size_t i = ((size_t)blockIdx.x * 256 + threadIdx.x) * 8;
  const int n = (int)(i >> 9);
  const int c = (int)(i & 511);
  const float m1 = s1v[n], inv = rowinv[n];
  const float em1 = expf(m1);
  const float* src = UqBase + spark_row(n) + c;
  float4 r0 = *(const float4*)(src);
  float4 r1 = *(const float4*)(src + 4);
  float vv[8] = {r0.x, r0.y, r0.z, r0.w, r1.x, r1.y, r1.z, r1.w};
  float sm[8], sq[8];
  #pragma unroll
  for (int k = 0; k < 8; ++k){
    float e = expf(vv[k] - m1);
    sm[k] = e * inv;
    sq[k] = e * em1 / colsum[c + k];
  }
  *(float4*)(SM + i)     = (float4){sm[0], sm[1], sm[2], sm[3]};
  *(float4*)(SM + i + 4) = (float4){sm[4], sm[5], sm[6], sm[7]};
  *(float4*)(SQ + i)     = (float4){sq[0], sq[1], sq[2], sq[3]};
  *(float4*)(SQ + i + 4) = (float4){sq[4], sq[5], sq[6], sq[7]};
}

// ---- K6: concat = score_memory @ keys -> updated_query[:, 512:] (f32 strided channels).
// A: f32 SM converted to bf16 during staging. B: kt (keys^T) bf16.
__global__ __launch_bounds__(256) void k6_concat(const float* __restrict__ Ap,
    const u16* __restrict__ BkT, float* __restrict__ Uq)
{
  __shared__ __align__(16) char smem[16384];
  const int t = threadIdx.x;
  const int lane = t & 63;
  const int wid = t >> 6;
  const int l15 = lane & 15, l4 = lane >> 4;
  const int n0 = blockIdx.x * 128;
  const int j0 = blockIdx.y * 128;     // output channel block
  const int wr = (wid & 1) * 64;
  const int wc = (wid >> 1) * 64;
  const int rA = t >> 2;
  const int ch = t & 3;

  f32x4 acc[4][4];
  #pragma unroll
  for (int a = 0; a < 4; ++a)
    #pragma unroll
    for (int b = 0; b < 4; ++b) acc[a][b] = (f32x4){0.f, 0.f, 0.f, 0.f};

  const size_t arow0 = (size_t)(n0 + rA) * DIMS;
  const size_t arow1 = (size_t)(n0 + 64 + rA) * DIMS;
  const size_t brow0 = (size_t)(j0 + rA) * DIMS;
  const size_t brow1 = (size_t)(j0 + 64 + rA) * DIMS;
  const int choff = ch * 8;
  char* As = smem;
  char* Bs = smem + 8192;
  const int sw = (ch ^ ((rA >> 1) & 3)) * 16;
  const int dst0 = rA * 64 + sw;
  const int dst1 = (64 + rA) * 64 + sw;

  float4 fa00 = *(const float4*)(Ap + arow0 + choff);
  float4 fa01 = *(const float4*)(Ap + arow0 + choff + 4);
  float4 fa10 = *(const float4*)(Ap + arow1 + choff);
  float4 fa11 = *(const float4*)(Ap + arow1 + choff + 4);
  uint4 b0 = *(const uint4*)(BkT + brow0 + choff);
  uint4 b1 = *(const uint4*)(BkT + brow1 + choff);

  for (int kk = 0; kk < 16; ++kk){
    uint4 a0 = make_uint4(pack2(fa00.x, fa00.y), pack2(fa00.z, fa00.w),
                          pack2(fa01.x, fa01.y), pack2(fa01.z, fa01.w));
    uint4 a1 = make_uint4(pack2(fa10.x, fa10.y), pack2(fa10.z, fa10.w),
                          pack2(fa11.x, fa11.y), pack2(fa11.z, fa11.w));
    __syncthreads();
    *(uint4*)(As + dst0) = a0;
    *(uint4*)(As + dst1) = a1;
    *(uint4*)(Bs + dst0) = b0;
    *(uint4*)(Bs + dst1) = b1;
    __syncthreads();
    if (kk < 15){
      const int ko = (kk + 1) * 32 + choff;
      fa00 = *(const float4*)(Ap + arow0 + ko);
      fa01 = *(const float4*)(Ap + arow0 + ko + 4);
      fa10 = *(const float4*)(Ap + arow1 + ko);
      fa11 = *(const float4*)(Ap + arow1 + ko + 4);
      b0 = *(const uint4*)(BkT + brow0 + ko);
      b1 = *(const uint4*)(BkT + brow1 + ko);
    }
    bf16x8 af[4], bfr[4];
    #pragma unroll
    for (int mi = 0; mi < 4; ++mi){
      int rr = wr + mi * 16 + l15;
      af[mi] = *(const bf16x8*)(As + rr * 64 + ((l4 ^ ((rr >> 1) & 3)) * 16));
    }
    #pragma unroll
    for (int nj = 0; nj < 4; ++nj){
      int rr = wc + nj * 16 + l15;
      bfr[nj] = *(const bf16x8*)(Bs + rr * 64 + ((l4 ^ ((rr >> 1) & 3)) * 16));
    }
    #pragma unroll
    for (int mi = 0; mi < 4; ++mi)
      #pragma unroll
      for (int nj = 0; nj < 4; ++nj)
        acc[mi][nj] = __builtin_amdgcn_mfma_f32_16x16x32_bf16(af[mi], bfr[nj], acc[mi][nj], 0, 0, 0);
  }

  const int bq = n0 >> 10;
  const int p0 = n0 & 1023;
  #pragma unroll
  for (int nj = 0; nj < 4; ++nj){
    const size_t chn = (size_t)(bq * 1024 + 512 + j0 + wc + nj * 16 + l15) * 1024;
    #pragma unroll
    for (int mi = 0; mi < 4; ++mi){
      f32x4 v = acc[mi][nj];
      *(float4*)(Uq + chn + p0 + wr + mi * 16 + l4 * 4) = (float4){v[0], v[1], v[2], v[3]};
    }
  }
}

// ---- K9: reduce per-block loss partials -> scalar f32 outputs.
__global__ __launch_bounds__(256) void k9_fin(const float* __restrict__ part,
    float* __restrict__ outL)
{
  const int t = threadIdx.x;
  float gs = 0.f, ss = 0.f;
  for (int i = t; i < 16384; i += 256){ gs += part[2 * i]; ss += part[2 * i + 1]; }
  #pragma unroll
  for (int d = 1; d < 64; d <<= 1){ gs += __shfl_xor(gs, d); ss += __shfl_xor(ss, d); }
  __shared__ float rg[4], rs2[4];
  if ((t & 63) == 0){ rg[t >> 6] = gs; rs2[t >> 6] = ss; }
  __syncthreads();
  if (t == 0){
    float G = rg[0] + rg[1] + rg[2] + rg[3];
    float S = rs2[0] + rs2[1] + rs2[2] + rs2[3];
    outL[0] = G / (65536.0f * 512.0f);
    outL[1] = S / 65536.0f;
  }
}

extern "C" void kernel_launch(void* const* d_in, const int* in_sizes, int n_in,
                              void* d_out, int out_size, void* d_ws, size_t ws_size,
                              hipStream_t stream)
{
  // query = 33,554,432-element tensor, keys = 262,144, regardless of ordering.
  int qi = 0, ki = 1;
  if (n_in >= 2 && in_sizes[0] < in_sizes[1]){ qi = 1; ki = 0; }
  const float* query = (const float*)d_in[qi];
  const float* keys  = (const float*)d_in[ki];
  float* out = (float*)d_out;

  // output offsets (f32 elements)
  const size_t OFF_UQ = 0;
  const size_t OFF_UM = 67108864;
  const size_t OFF_SQ = 67371008;
  const size_t OFF_SM = 100925440;
  const size_t OFF_GL = 134479872;

  // q_bf16 [N][512] parked in the first half of the score_memory f32 region until K7.
  u16* qb = (u16*)(out + OFF_SM);

  // workspace layout (~2.24 MB total)
  char* ws = (char*)d_ws;
  u16*   kb     = (u16*)ws;                       //   524,288 B
  u16*   kt     = (u16*)(ws + 524288);            //   524,288
  float* sumq   = (float*)(ws + 1048576);         //   262,144
  int*   gidx   = (int*)(ws + 1310720);           //   262,144
  float* s1v    = (float*)(ws + 1572864);         //   262,144
  float* rowinv = (float*)(ws + 1835008);         //   262,144
  float* part   = (float*)(ws + 2097152);         //   131,072
  float* kn2    = (float*)(ws + 2228224);         //     2,048
  float* ksum   = (float*)(ws + 2230272);         //     2,048
  u32*   colmax = (u32*)(ws + 2232320);           //     2,048
  float* colsum = (float*)(ws + 2234368);         //     2,048

  k0_prep<<<512, 512, 0, stream>>>(keys, kb, kt, kn2, ksum, colmax, colsum);
  k1_norm<<<dim3(16, 64), 256, 0, stream>>>(query, out + OFF_UQ, qb, sumq);
  k2_score<<<dim3(512, 4), 256, 0, stream>>>(qb, kb, out + OFF_UQ, colmax, colsum);
  k3_row<<<16384, 256, 0, stream>>>(out + OFF_UQ, gidx, s1v, rowinv, kn2, ksum, sumq, part);
  k7_update<<<512, 256, 0, stream>>>(gidx, s1v, colmax, qb, keys, out + OFF_UM);
  k58_smsq<<<16384, 256, 0, stream>>>(out + OFF_UQ, s1v, rowinv, colsum,
                                      out + OFF_SM, out + OFF_SQ);
  k6_concat<<<dim3(512, 4), 256, 0, stream>>>(out + OFF_SM, kt, out + OFF_UQ);
  k9_fin<<<1, 256, 0, stream>>>(part, out + OFF_GL);
}

// Round 7
// 436.221 us; speedup vs baseline: 1.5169x; 1.2682x over previous
//
#include <hip/hip_runtime.h>
#include <stdint.h>

// B=64, C=512, H=W=32 -> N=65536 pixels, m=512 slots, d=512 dims.
// Inputs f32: query (33,554,432 elems), keys (262,144) -- selected by size.
// Output f32 concat: updated_query [64][1024][32][32] | updated_memory [512][512]
//   | score_query [65536][512] | score_memory [65536][512] | g_loss | s_loss
//
// R7: full-row-tile fusion. 6 kernels, ~1.0 GB HBM traffic:
//  K0  keys prep (kb, kt bf16; ||k||^2; sum k; zero colmax/colsum)
//  K1  norm: q->UQ low f32; qb bf16 -> SQ-region; sumq
//  K2f score GEMM 64rows x 512cols/block: SM=exp(s)/rowtot direct, top2/gidx/s1v/rfac,
//      colmax+colsum atomics, loss partials. Raw S never hits HBM.
//  K7  memory update (reads qb)                      [qb dies here]
//  K6f concat GEMM (A=keys^T L2-resident, B=SM read once, f32->bf16 staging):
//      UQ high channels + SQ = SM*rfac/colsum side-write (overwrites qb corpse)
//  K9  loss reduce (1024 partials)

typedef unsigned int u32;
typedef unsigned long long u64;
typedef unsigned short u16;

typedef float f32x4 __attribute__((ext_vector_type(4)));
typedef short bf16x8 __attribute__((ext_vector_type(8)));

#define DIMS 512

__device__ __forceinline__ u16 f2bf(float x){
  u32 u = __float_as_uint(x);
  return (u16)((u + 0x7FFFu + ((u >> 16) & 1u)) >> 16);
}
__device__ __forceinline__ float bf2f(u16 h){ return __uint_as_float(((u32)h) << 16); }
__device__ __forceinline__ u32 pack2(float a, float b){
  return (u32)f2bf(a) | ((u32)f2bf(b) << 16);
}
__device__ __forceinline__ u32 fkey(float x){
  u32 b = __float_as_uint(x);
  return (b & 0x80000000u) ? ~b : (b | 0x80000000u);
}
__device__ __forceinline__ float fdec(u32 u){
  return (u & 0x80000000u) ? __uint_as_float(u & 0x7FFFFFFFu) : __uint_as_float(~u);
}

// ---- K0: keys prep. 512 blocks x 512 threads.
__global__ __launch_bounds__(512) void k0_prep(const float* __restrict__ keys,
    u16* __restrict__ kb, u16* __restrict__ kt,
    float* __restrict__ kn2, float* __restrict__ ksum,
    u32* __restrict__ colmax_u, float* __restrict__ colsum)
{
  const int j = blockIdx.x, t = threadIdx.x;
  float v = keys[(size_t)j * 512 + t];
  u16 h = f2bf(v);
  kb[(size_t)j * 512 + t] = h;
  kt[(size_t)t * 512 + j] = h;
  float s = v, ss = v * v;
  #pragma unroll
  for (int d = 1; d < 64; d <<= 1){ s += __shfl_xor(s, d); ss += __shfl_xor(ss, d); }
  __shared__ float rs[8], rss[8];
  const int w = t >> 6, lane = t & 63;
  if (lane == 0){ rs[w] = s; rss[w] = ss; }
  __syncthreads();
  if (t == 0){
    float S = 0.f, SS = 0.f;
    for (int i = 0; i < 8; ++i){ S += rs[i]; SS += rss[i]; }
    ksum[j] = S; kn2[j] = SS;
  }
  if (j == 0){ colmax_u[t] = 0u; colsum[t] = 0.f; }
}

// ---- K1: channel L2-normalize (single pass, 128 regs). q f32 -> UQ low; qb bf16
// row-major -> SQ region; per-pixel sum(q). grid (16,64), 256 threads.
__global__ __launch_bounds__(256) void k1_norm(const float* __restrict__ query,
    float* __restrict__ uq, u16* __restrict__ qb, float* __restrict__ sumq)
{
  __shared__ float red[4][64];
  __shared__ float rinvS[64];
  __shared__ float T[64][65];
  const int t = threadIdx.x;
  const int p = t & 63;
  const int cq = t >> 6;
  const int b = blockIdx.y;
  const int p0 = blockIdx.x * 64;
  const float* base = query + (size_t)b * 524288 + p0;

  float v[128];
  float ssq = 0.f;
  #pragma unroll
  for (int k = 0; k < 128; ++k){
    float x = base[(size_t)(cq + 4 * k) * 1024 + p];
    v[k] = x; ssq += x * x;
  }
  red[cq][p] = ssq;
  __syncthreads();
  if (t < 64){
    float tot = red[0][t] + red[1][t] + red[2][t] + red[3][t];
    rinvS[t] = 1.0f / fmaxf(sqrtf(tot), 1e-12f);
  }
  __syncthreads();
  const float rinv = rinvS[p];
  float* uqo = uq + (size_t)b * 1048576 + p0;
  float mysum = 0.f;
  const int r = t >> 2, seg = t & 3;
  for (int cb = 0; cb < 8; ++cb){
    #pragma unroll
    for (int i = 0; i < 16; ++i){
      int c = cb * 64 + cq + i * 4;
      float x = v[cb * 16 + i] * rinv;
      uqo[(size_t)c * 1024 + p] = x;
      T[cq + i * 4][p] = x;
      mysum += x;
    }
    __syncthreads();
    {
      u32 wpk[8];
      #pragma unroll
      for (int k = 0; k < 8; ++k)
        wpk[k] = pack2(T[seg * 16 + 2 * k][r], T[seg * 16 + 2 * k + 1][r]);
      uint4* dst = (uint4*)(qb + ((size_t)(b * 1024 + p0 + r)) * 512 + cb * 64 + seg * 16);
      dst[0] = make_uint4(wpk[0], wpk[1], wpk[2], wpk[3]);
      dst[1] = make_uint4(wpk[4], wpk[5], wpk[6], wpk[7]);
    }
    __syncthreads();
  }
  red[cq][p] = mysum;
  __syncthreads();
  if (t < 64)
    sumq[(size_t)b * 1024 + p0 + t] = red[0][t] + red[1][t] + red[2][t] + red[3][t];
}

// ---- K2f: fused score GEMM + row stats + SM + col atomics + losses.
// 1024 blocks x 512 threads (8 waves). Block: 64 N-rows x all 512 slots, BK=32.
// Wave w covers slot strip w*64..w*64+63.
__global__ __launch_bounds__(512) void k2f(const u16* __restrict__ Aq,
    const u16* __restrict__ Bk, float* __restrict__ SM,
    u32* __restrict__ colmax_u, float* __restrict__ colsum,
    int* __restrict__ gidx, float* __restrict__ s1v, float* __restrict__ rfac,
    const float* __restrict__ kn2, const float* __restrict__ ksum,
    const float* __restrict__ sumq, float* __restrict__ part)
{
  __shared__ __align__(16) char As[4096];    // 64 rows x 32 bf16 (64 B/row)
  __shared__ __align__(16) char Bs[32768];   // 512 rows x 32 bf16
  __shared__ float rs_m1[8][64], rs_m2[8][64], rs_es[8][64];
  __shared__ int   rs_i1[8][64], rs_i2[8][64];
  __shared__ float rtinv[64];

  const int t = threadIdx.x;
  const int w = t >> 6;
  const int lane = t & 63;
  const int l15 = lane & 15, l4 = lane >> 4;
  const int n0 = blockIdx.x * 64;

  f32x4 acc[4][4];
  #pragma unroll
  for (int a = 0; a < 4; ++a)
    #pragma unroll
    for (int b = 0; b < 4; ++b) acc[a][b] = (f32x4){0.f, 0.f, 0.f, 0.f};

  const int rA = t >> 2;            // A: 0..63 (t<256); B: rB = 0..127
  const int ch = t & 3;
  const int choff = ch * 8;
  const int swA = ((ch ^ ((rA >> 1) & 3)) * 16);
  const int dA = rA * 64 + swA;

  uint4 a0, b0, b1, b2, b3;
  if (t < 256) a0 = *(const uint4*)(Aq + (size_t)(n0 + rA) * 512 + choff);
  b0 = *(const uint4*)(Bk + (size_t)(rA)       * 512 + choff);
  b1 = *(const uint4*)(Bk + (size_t)(rA + 128) * 512 + choff);
  b2 = *(const uint4*)(Bk + (size_t)(rA + 256) * 512 + choff);
  b3 = *(const uint4*)(Bk + (size_t)(rA + 384) * 512 + choff);

  for (int kk = 0; kk < 16; ++kk){
    __syncthreads();
    if (t < 256) *(uint4*)(As + dA) = a0;
    *(uint4*)(Bs + dA)              = b0;   // sigma(r+128k)==sigma(r)
    *(uint4*)(Bs + dA + 128 * 64)   = b1;
    *(uint4*)(Bs + dA + 256 * 64)   = b2;
    *(uint4*)(Bs + dA + 384 * 64)   = b3;
    __syncthreads();
    if (kk < 15){
      const int ko = (kk + 1) * 32 + choff;
      if (t < 256) a0 = *(const uint4*)(Aq + (size_t)(n0 + rA) * 512 + ko);
      b0 = *(const uint4*)(Bk + (size_t)(rA)       * 512 + ko);
      b1 = *(const uint4*)(Bk + (size_t)(rA + 128) * 512 + ko);
      b2 = *(const uint4*)(Bk + (size_t)(rA + 256) * 512 + ko);
      b3 = *(const uint4*)(Bk + (size_t)(rA + 384) * 512 + ko);
    }
    bf16x8 af[4], bf[4];
    #pragma unroll
    for (int mi = 0; mi < 4; ++mi){
      int rr = mi * 16 + l15;
      af[mi] = *(const bf16x8*)(As + rr * 64 + ((l4 ^ ((rr >> 1) & 3)) * 16));
    }
    #pragma unroll
    for (int nj = 0; nj < 4; ++nj){
      int rb = w * 64 + nj * 16 + l15;
      bf[nj] = *(const bf16x8*)(Bs + rb * 64 + ((l4 ^ ((rb >> 1) & 3)) * 16));
    }
    #pragma unroll
    for (int mi = 0; mi < 4; ++mi)
      #pragma unroll
      for (int nj = 0; nj < 4; ++nj)
        acc[mi][nj] = __builtin_amdgcn_mfma_f32_16x16x32_bf16(af[mi], bf[nj], acc[mi][nj], 0, 0, 0);
  }

  // acc[mi][nj][e]: row = mi*16 + l4*4 + e (N), col = w*64 + nj*16 + l15 (slot).
  // (1) per-row top2 over this wave's 64-col strip (raw values).
  #pragma unroll
  for (int mi = 0; mi < 4; ++mi){
    #pragma unroll
    for (int e = 0; e < 4; ++e){
      const int row = mi * 16 + l4 * 4 + e;
      float m1 = -3e38f, m2 = -3e38f; int i1 = 0x7FFFFFFF, i2 = 0x7FFFFFFF;
      #pragma unroll
      for (int nj = 0; nj < 4; ++nj){
        float val = acc[mi][nj][e];
        int idx = w * 64 + nj * 16 + l15;
        if (val > m1){ m2 = m1; i2 = i1; m1 = val; i1 = idx; }
        else if (val > m2){ m2 = val; i2 = idx; }
      }
      #pragma unroll
      for (int d = 1; d < 16; d <<= 1){
        float o1 = __shfl_xor(m1, d), o2 = __shfl_xor(m2, d);
        int oi1 = __shfl_xor(i1, d), oi2 = __shfl_xor(i2, d);
        if (o1 > m1 || (o1 == m1 && oi1 < i1)){
          if (m1 > o2 || (m1 == o2 && i1 < oi2)){ m2 = m1; i2 = i1; }
          else { m2 = o2; i2 = oi2; }
          m1 = o1; i1 = oi1;
        } else {
          if (o1 > m2 || (o1 == m2 && oi1 < i2)){ m2 = o1; i2 = oi1; }
        }
      }
      if (l15 == 0){
        rs_m1[w][row] = m1; rs_i1[w][row] = i1;
        rs_m2[w][row] = m2; rs_i2[w][row] = i2;
      }
    }
  }
  // (2) col max on raw values.
  #pragma unroll
  for (int nj = 0; nj < 4; ++nj){
    float cm = -3e38f;
    #pragma unroll
    for (int mi = 0; mi < 4; ++mi)
      #pragma unroll
      for (int e = 0; e < 4; ++e) cm = fmaxf(cm, acc[mi][nj][e]);
    cm = fmaxf(cm, __shfl_xor(cm, 16));
    cm = fmaxf(cm, __shfl_xor(cm, 32));
    if (l4 == 0) atomicMax(&colmax_u[w * 64 + nj * 16 + l15], fkey(cm));
  }
  // (3) exp in place; (4) row / col sums.
  #pragma unroll
  for (int mi = 0; mi < 4; ++mi)
    #pragma unroll
    for (int nj = 0; nj < 4; ++nj)
      #pragma unroll
      for (int e = 0; e < 4; ++e) acc[mi][nj][e] = expf(acc[mi][nj][e]);
  #pragma unroll
  for (int mi = 0; mi < 4; ++mi){
    #pragma unroll
    for (int e = 0; e < 4; ++e){
      const int row = mi * 16 + l4 * 4 + e;
      float ps = acc[mi][0][e] + acc[mi][1][e] + acc[mi][2][e] + acc[mi][3][e];
      #pragma unroll
      for (int d = 1; d < 16; d <<= 1) ps += __shfl_xor(ps, d);
      if (l15 == 0) rs_es[w][row] = ps;
    }
  }
  #pragma unroll
  for (int nj = 0; nj < 4; ++nj){
    float cs = 0.f;
    #pragma unroll
    for (int mi = 0; mi < 4; ++mi)
      #pragma unroll
      for (int e = 0; e < 4; ++e) cs += acc[mi][nj][e];
    cs += __shfl_xor(cs, 16);
    cs += __shfl_xor(cs, 32);
    if (l4 == 0) atomicAdd(&colsum[w * 64 + nj * 16 + l15], cs);
  }
  __syncthreads();
  // (5) cross-wave combine by wave 0 (one row per lane); stats, losses.
  if (t < 64){
    const int row = t, n = n0 + row;
    float m1 = -3e38f, m2 = -3e38f; int i1 = 0x7FFFFFFF, i2 = 0x7FFFFFFF;
    float tot = 0.f;
    #pragma unroll
    for (int w2 = 0; w2 < 8; ++w2){
      float o1 = rs_m1[w2][row], o2 = rs_m2[w2][row];
      int oi1 = rs_i1[w2][row], oi2 = rs_i2[w2][row];
      tot += rs_es[w2][row];
      if (o1 > m1 || (o1 == m1 && oi1 < i1)){
        if (m1 > o2 || (m1 == o2 && i1 < oi2)){ m2 = m1; i2 = i1; }
        else { m2 = o2; i2 = oi2; }
        m1 = o1; i1 = oi1;
      } else {
        if (o1 > m2 || (o1 == m2 && oi1 < i2)){ m2 = o1; i2 = oi1; }
      }
    }
    gidx[n] = i1; s1v[n] = m1; rfac[n] = tot;
    rtinv[row] = 1.0f / tot;
    float sq = sumq[n];
    float gl = 1.0f + kn2[i1] - 2.0f * m1;
    float dp2 = gl + 2e-6f * (sq - ksum[i1]) + 5.12e-10f;
    float dn2 = 1.0f + kn2[i2] - 2.0f * m2 + 2e-6f * (sq - ksum[i2]) + 5.12e-10f;
    float sl = fmaxf(sqrtf(dp2) - sqrtf(dn2) + 1.0f, 0.0f);
    #pragma unroll
    for (int d = 1; d < 64; d <<= 1){ gl += __shfl_xor(gl, d); sl += __shfl_xor(sl, d); }
    if (t == 0){ part[2 * blockIdx.x] = gl; part[2 * blockIdx.x + 1] = sl; }
  }
  __syncthreads();
  // (6) SM = exp(s) / rowtot.
  #pragma unroll
  for (int mi = 0; mi < 4; ++mi){
    #pragma unroll
    for (int e = 0; e < 4; ++e){
      const int row = mi * 16 + l4 * 4 + e;
      const float ri = rtinv[row];
      float* dst = SM + (size_t)(n0 + row) * 512 + w * 64 + l15;
      #pragma unroll
      for (int nj = 0; nj < 4; ++nj)
        dst[nj * 16] = acc[mi][nj][e] * ri;
    }
  }
}

// ---- K7: memory update. One block per slot j; wgt = exp(s1 - cm). Reads qb.
__global__ __launch_bounds__(256) void k7_update(const int* __restrict__ gidx,
    const float* __restrict__ s1v, const u32* __restrict__ colmax_u,
    const u16* __restrict__ qb, const float* __restrict__ keys, float* __restrict__ um)
{
  const int j = blockIdx.x;
  const int t = threadIdx.x;
  const int lane = t & 63;
  const int w = t >> 6;
  const float cm = fdec(colmax_u[j]);
  float acc[8] = {0.f, 0.f, 0.f, 0.f, 0.f, 0.f, 0.f, 0.f};
  const int b0 = w * 16384, b1 = b0 + 16384;
  for (int base = b0; base < b1; base += 64){
    u64 mask = __ballot(gidx[base + lane] == j);
    while (mask){
      int bpos = (int)__builtin_ctzll(mask);
      mask &= mask - 1;
      int rrow = base + bpos;
      float wgt = expf(s1v[rrow] - cm);
      uint4 rv = *(const uint4*)(qb + (size_t)rrow * 512 + lane * 8);
      u32 a4[4] = {rv.x, rv.y, rv.z, rv.w};
      #pragma unroll
      for (int q = 0; q < 4; ++q){
        acc[2 * q]     += wgt * bf2f((u16)(a4[q] & 0xFFFFu));
        acc[2 * q + 1] += wgt * bf2f((u16)(a4[q] >> 16));
      }
    }
  }
  __shared__ float red[512];
  for (int i = t; i < 512; i += 256) red[i] = 0.f;
  __syncthreads();
  #pragma unroll
  for (int k = 0; k < 8; ++k) atomicAdd(&red[lane * 8 + k], acc[k]);
  __syncthreads();
  float v0 = red[t]       + keys[(size_t)j * 512 + t];
  float v1 = red[t + 256] + keys[(size_t)j * 512 + t + 256];
  float ssq = v0 * v0 + v1 * v1;
  #pragma unroll
  for (int d = 1; d < 64; d <<= 1) ssq += __shfl_xor(ssq, d);
  __shared__ float rr4[4];
  if (lane == 0) rr4[w] = ssq;
  __syncthreads();
  const float rinv = 1.0f / fmaxf(sqrtf(rr4[0] + rr4[1] + rr4[2] + rr4[3]), 1e-12f);
  um[(size_t)j * 512 + t]       = v0 * rinv;
  um[(size_t)j * 512 + t + 256] = v1 * rinv;
}

// ---- K6f: concat GEMM + SQ side-write. 1024 blocks x 512 threads.
// A = kt [512 ch][512 d] (L2-resident, staged fully), B = SM-tile [64 pix][32] f32->bf16.
// C[ch][pix] = (SM @ keys)[pix][ch] stored into channel-major UQ high half.
// During B staging: SQ[n][c] = SM * rfac[n] / colsum[c].
__global__ __launch_bounds__(512) void k6f(const float* __restrict__ SMf,
    const u16* __restrict__ kt, float* __restrict__ Uq, float* __restrict__ SQ,
    const float* __restrict__ rfac, const float* __restrict__ colsum)
{
  __shared__ __align__(16) char Ks[32768];   // 512 rows x 32 bf16
  __shared__ __align__(16) char Qs[4096];    // 64 rows x 32 bf16
  const int t = threadIdx.x;
  const int w = t >> 6;
  const int lane = t & 63;
  const int l15 = lane & 15, l4 = lane >> 4;
  const int n0 = blockIdx.x * 64;

  f32x4 acc[4][4];
  #pragma unroll
  for (int a = 0; a < 4; ++a)
    #pragma unroll
    for (int b = 0; b < 4; ++b) acc[a][b] = (f32x4){0.f, 0.f, 0.f, 0.f};

  const int rK = t >> 2;           // 0..127
  const int ch = t & 3;
  const int choff = ch * 8;
  const int dK = rK * 64 + ((ch ^ ((rK >> 1) & 3)) * 16);
  // Q staging: thread -> (row rQ, 4 cols at c4)
  const int rQ = t >> 3;           // 0..63
  const int c4 = (t & 7) * 4;      // 0..28
  const size_t qrow = (size_t)(n0 + rQ) * 512;
  const float rf = rfac[n0 + rQ];
  const int qdst = rQ * 64 + (((c4 >> 3) ^ ((rQ >> 1) & 3)) * 16) + ((c4 & 4) << 1);

  uint4 k0v, k1v, k2v, k3v; float4 q0;
  k0v = *(const uint4*)(kt + (size_t)(rK)       * 512 + choff);
  k1v = *(const uint4*)(kt + (size_t)(rK + 128) * 512 + choff);
  k2v = *(const uint4*)(kt + (size_t)(rK + 256) * 512 + choff);
  k3v = *(const uint4*)(kt + (size_t)(rK + 384) * 512 + choff);
  q0  = *(const float4*)(SMf + qrow + c4);

  for (int kk = 0; kk < 16; ++kk){
    __syncthreads();
    *(uint4*)(Ks + dK)            = k0v;
    *(uint4*)(Ks + dK + 128 * 64) = k1v;
    *(uint4*)(Ks + dK + 256 * 64) = k2v;
    *(uint4*)(Ks + dK + 384 * 64) = k3v;
    *(u32*)(Qs + qdst)     = pack2(q0.x, q0.y);
    *(u32*)(Qs + qdst + 4) = pack2(q0.z, q0.w);
    __syncthreads();
    // SQ side-write for this subtile (exactly-once coverage over kk)
    {
      float4 cs = *(const float4*)(colsum + kk * 32 + c4);
      float4 sq;
      sq.x = q0.x * rf / cs.x; sq.y = q0.y * rf / cs.y;
      sq.z = q0.z * rf / cs.z; sq.w = q0.w * rf / cs.w;
      *(float4*)(SQ + qrow + kk * 32 + c4) = sq;
    }
    if (kk < 15){
      const int ko = (kk + 1) * 32;
      k0v = *(const uint4*)(kt + (size_t)(rK)       * 512 + ko + choff);
      k1v = *(const uint4*)(kt + (size_t)(rK + 128) * 512 + ko + choff);
      k2v = *(const uint4*)(kt + (size_t)(rK + 256) * 512 + ko + choff);
      k3v = *(const uint4*)(kt + (size_t)(rK + 384) * 512 + ko + choff);
      q0  = *(const float4*)(SMf + qrow + ko + c4);
    }
    bf16x8 af[4], bf[4];
    #pragma unroll
    for (int mi = 0; mi < 4; ++mi){
      int rr = w * 64 + mi * 16 + l15;
      af[mi] = *(const bf16x8*)(Ks + rr * 64 + ((l4 ^ ((rr >> 1) & 3)) * 16));
    }
    #pragma unroll
    for (int nj = 0; nj < 4; ++nj){
      int rb = nj * 16 + l15;
      bf[nj] = *(const bf16x8*)(Qs + rb * 64 + ((l4 ^ ((rb >> 1) & 3)) * 16));
    }
    #pragma unroll
    for (int mi = 0; mi < 4; ++mi)
      #pragma unroll
      for (int nj = 0; nj < 4; ++nj)
        acc[mi][nj] = __builtin_amdgcn_mfma_f32_16x16x32_bf16(af[mi], bf[nj], acc[mi][nj], 0, 0, 0);
  }

  // C row = channel = w*64 + mi*16 + l4*4 + e ; col = pixel = nj*16 + l15.
  const int bq = n0 >> 10;
  const int p0 = n0 & 1023;
  #pragma unroll
  for (int mi = 0; mi < 4; ++mi){
    #pragma unroll
    for (int e = 0; e < 4; ++e){
      const int chn = w * 64 + mi * 16 + l4 * 4 + e;
      float* dst = Uq + (size_t)(bq * 1024 + 512 + chn) * 1024 + p0 + l15;
      #pragma unroll
      for (int nj = 0; nj < 4; ++nj)
        dst[nj * 16] = acc[mi][nj][e];
    }
  }
}

// ---- K9: reduce 1024 per-block loss partials -> scalar f32 outputs.
__global__ __launch_bounds__(256) void k9_fin(const float* __restrict__ part,
    float* __restrict__ outL)
{
  const int t = threadIdx.x;
  float gs = 0.f, ss = 0.f;
  for (int i = t; i < 1024; i += 256){ gs += part[2 * i]; ss += part[2 * i + 1]; }
  #pragma unroll
  for (int d = 1; d < 64; d <<= 1){ gs += __shfl_xor(gs, d); ss += __shfl_xor(ss, d); }
  __shared__ float rg[4], rs2[4];
  if ((t & 63) == 0){ rg[t >> 6] = gs; rs2[t >> 6] = ss; }
  __syncthreads();
  if (t == 0){
    float G = rg[0] + rg[1] + rg[2] + rg[3];
    float S = rs2[0] + rs2[1] + rs2[2] + rs2[3];
    outL[0] = G / (65536.0f * 512.0f);
    outL[1] = S / 65536.0f;
  }
}

extern "C" void kernel_launch(void* const* d_in, const int* in_sizes, int n_in,
                              void* d_out, int out_size, void* d_ws, size_t ws_size,
                              hipStream_t stream)
{
  int qi = 0, ki = 1;
  if (n_in >= 2 && in_sizes[0] < in_sizes[1]){ qi = 1; ki = 0; }
  const float* query = (const float*)d_in[qi];
  const float* keys  = (const float*)d_in[ki];
  float* out = (float*)d_out;

  // output offsets (f32 elements)
  const size_t OFF_UQ = 0;
  const size_t OFF_UM = 67108864;
  const size_t OFF_SQ = 67371008;
  const size_t OFF_SM = 100925440;
  const size_t OFF_GL = 134479872;

  // qb bf16 [N][512] parked in first half of the SQ region until K7; K6f overwrites.
  u16* qb = (u16*)(out + OFF_SQ);

  // workspace (~2.1 MB)
  char* ws = (char*)d_ws;
  u16*   kb     = (u16*)ws;                       //   524,288 B
  u16*   kt     = (u16*)(ws + 524288);            //   524,288
  float* sumq   = (float*)(ws + 1048576);         //   262,144
  int*   gidx   = (int*)(ws + 1310720);           //   262,144
  float* s1v    = (float*)(ws + 1572864);         //   262,144
  float* rfac   = (float*)(ws + 1835008);         //   262,144
  float* part   = (float*)(ws + 2097152);         //     8,192
  float* kn2    = (float*)(ws + 2105344);         //     2,048
  float* ksum   = (float*)(ws + 2107392);         //     2,048
  u32*   colmax = (u32*)(ws + 2109440);           //     2,048
  float* colsum = (float*)(ws + 2111488);         //     2,048

  k0_prep<<<512, 512, 0, stream>>>(keys, kb, kt, kn2, ksum, colmax, colsum);
  k1_norm<<<dim3(16, 64), 256, 0, stream>>>(query, out + OFF_UQ, qb, sumq);
  k2f<<<1024, 512, 0, stream>>>(qb, kb, out + OFF_SM, colmax, colsum,
                                gidx, s1v, rfac, kn2, ksum, sumq, part);
  k7_update<<<512, 256, 0, stream>>>(gidx, s1v, colmax, qb, keys, out + OFF_UM);
  k6f<<<1024, 512, 0, stream>>>(out + OFF_SM, kt, out + OFF_UQ, out + OFF_SQ,
                                rfac, colsum);
  k9_fin<<<1, 256, 0, stream>>>(part, out + OFF_GL);
}

// Round 8
// 384.538 us; speedup vs baseline: 1.7208x; 1.1344x over previous
//
#include <hip/hip_runtime.h>
#include <stdint.h>

// B=64, C=512, H=W=32 -> N=65536 pixels, m=512 slots, d=512 dims.
// Inputs f32: query (33,554,432 elems), keys (262,144) -- selected by size.
// Output f32 concat: updated_query [64][1024][32][32] | updated_memory [512][512]
//   | score_query [65536][512] | score_memory [65536][512] | g_loss | s_loss
//
// R8: R7 pipeline + global_load_lds(16B) staging for all direct-copy GEMM tiles
// (K2f A/B, K6f Ks). Swizzle preserved by pre-swizzled per-lane global source
// (LDS dest linear); ds_read side unchanged -> LDS content byte-identical to R7.

typedef unsigned int u32;
typedef unsigned long long u64;
typedef unsigned short u16;

typedef float f32x4 __attribute__((ext_vector_type(4)));
typedef short bf16x8 __attribute__((ext_vector_type(8)));

#define DIMS 512

__device__ __forceinline__ u16 f2bf(float x){
  u32 u = __float_as_uint(x);
  return (u16)((u + 0x7FFFu + ((u >> 16) & 1u)) >> 16);
}
__device__ __forceinline__ float bf2f(u16 h){ return __uint_as_float(((u32)h) << 16); }
__device__ __forceinline__ u32 pack2(float a, float b){
  return (u32)f2bf(a) | ((u32)f2bf(b) << 16);
}
__device__ __forceinline__ u32 fkey(float x){
  u32 b = __float_as_uint(x);
  return (b & 0x80000000u) ? ~b : (b | 0x80000000u);
}
__device__ __forceinline__ float fdec(u32 u){
  return (u & 0x80000000u) ? __uint_as_float(u & 0x7FFFFFFFu) : __uint_as_float(~u);
}
// async global->LDS, 16 B per lane (wave-level: LDS dest = base + lane*16)
__device__ __forceinline__ void gload16(char* lds, const void* g){
  __builtin_amdgcn_global_load_lds(
      (const __attribute__((address_space(1))) u32*)g,
      (__attribute__((address_space(3))) u32*)lds, 16, 0, 0);
}

// ---- K0: keys prep. 512 blocks x 512 threads.
__global__ __launch_bounds__(512) void k0_prep(const float* __restrict__ keys,
    u16* __restrict__ kb, u16* __restrict__ kt,
    float* __restrict__ kn2, float* __restrict__ ksum,
    u32* __restrict__ colmax_u, float* __restrict__ colsum)
{
  const int j = blockIdx.x, t = threadIdx.x;
  float v = keys[(size_t)j * 512 + t];
  u16 h = f2bf(v);
  kb[(size_t)j * 512 + t] = h;
  kt[(size_t)t * 512 + j] = h;
  float s = v, ss = v * v;
  #pragma unroll
  for (int d = 1; d < 64; d <<= 1){ s += __shfl_xor(s, d); ss += __shfl_xor(ss, d); }
  __shared__ float rs[8], rss[8];
  const int w = t >> 6, lane = t & 63;
  if (lane == 0){ rs[w] = s; rss[w] = ss; }
  __syncthreads();
  if (t == 0){
    float S = 0.f, SS = 0.f;
    for (int i = 0; i < 8; ++i){ S += rs[i]; SS += rss[i]; }
    ksum[j] = S; kn2[j] = SS;
  }
  if (j == 0){ colmax_u[t] = 0u; colsum[t] = 0.f; }
}

// ---- K1: channel L2-normalize (single pass, 128 regs). q f32 -> UQ low; qb bf16
// row-major -> SQ region; per-pixel sum(q). grid (16,64), 256 threads.
__global__ __launch_bounds__(256) void k1_norm(const float* __restrict__ query,
    float* __restrict__ uq, u16* __restrict__ qb, float* __restrict__ sumq)
{
  __shared__ float red[4][64];
  __shared__ float rinvS[64];
  __shared__ float T[64][65];
  const int t = threadIdx.x;
  const int p = t & 63;
  const int cq = t >> 6;
  const int b = blockIdx.y;
  const int p0 = blockIdx.x * 64;
  const float* base = query + (size_t)b * 524288 + p0;

  float v[128];
  float ssq = 0.f;
  #pragma unroll
  for (int k = 0; k < 128; ++k){
    float x = base[(size_t)(cq + 4 * k) * 1024 + p];
    v[k] = x; ssq += x * x;
  }
  red[cq][p] = ssq;
  __syncthreads();
  if (t < 64){
    float tot = red[0][t] + red[1][t] + red[2][t] + red[3][t];
    rinvS[t] = 1.0f / fmaxf(sqrtf(tot), 1e-12f);
  }
  __syncthreads();
  const float rinv = rinvS[p];
  float* uqo = uq + (size_t)b * 1048576 + p0;
  float mysum = 0.f;
  const int r = t >> 2, seg = t & 3;
  for (int cb = 0; cb < 8; ++cb){
    #pragma unroll
    for (int i = 0; i < 16; ++i){
      int c = cb * 64 + cq + i * 4;
      float x = v[cb * 16 + i] * rinv;
      uqo[(size_t)c * 1024 + p] = x;
      T[cq + i * 4][p] = x;
      mysum += x;
    }
    __syncthreads();
    {
      u32 wpk[8];
      #pragma unroll
      for (int k = 0; k < 8; ++k)
        wpk[k] = pack2(T[seg * 16 + 2 * k][r], T[seg * 16 + 2 * k + 1][r]);
      uint4* dst = (uint4*)(qb + ((size_t)(b * 1024 + p0 + r)) * 512 + cb * 64 + seg * 16);
      dst[0] = make_uint4(wpk[0], wpk[1], wpk[2], wpk[3]);
      dst[1] = make_uint4(wpk[4], wpk[5], wpk[6], wpk[7]);
    }
    __syncthreads();
  }
  red[cq][p] = mysum;
  __syncthreads();
  if (t < 64)
    sumq[(size_t)b * 1024 + p0 + t] = red[0][t] + red[1][t] + red[2][t] + red[3][t];
}

// ---- K2f: fused score GEMM + row stats + SM + col atomics + losses.
// 1024 blocks x 512 threads (8 waves). Block: 64 N-rows x all 512 slots, BK=32.
// Staging via global_load_lds: LDS pos (r,p) holds global chunk (p ^ sigma(r)),
// sigma(r) = (r>>1)&3 -- achieved by XOR on the per-lane SOURCE address.
__global__ __launch_bounds__(512) void k2f(const u16* __restrict__ Aq,
    const u16* __restrict__ Bk, float* __restrict__ SM,
    u32* __restrict__ colmax_u, float* __restrict__ colsum,
    int* __restrict__ gidx, float* __restrict__ s1v, float* __restrict__ rfac,
    const float* __restrict__ kn2, const float* __restrict__ ksum,
    const float* __restrict__ sumq, float* __restrict__ part)
{
  __shared__ __align__(16) char As[4096];    // 64 rows x 32 bf16
  __shared__ __align__(16) char Bs[32768];   // 512 rows x 32 bf16
  __shared__ float rs_m1[8][64], rs_m2[8][64], rs_es[8][64];
  __shared__ int   rs_i1[8][64], rs_i2[8][64];
  __shared__ float rtinv[64];

  const int t = threadIdx.x;
  const int w = t >> 6;
  const int lane = t & 63;
  const int l15 = lane & 15, l4 = lane >> 4;
  const int n0 = blockIdx.x * 64;

  f32x4 acc[4][4];
  #pragma unroll
  for (int a = 0; a < 4; ++a)
    #pragma unroll
    for (int b = 0; b < 4; ++b) acc[a][b] = (f32x4){0.f, 0.f, 0.f, 0.f};

  // per-lane staging sources (pre-swizzled): chunk granularity 1024 B = 16 rows
  const int lrow = lane >> 2;      // 0..15
  const int lpos = lane & 3;
  const u16* srcB[4];
  #pragma unroll
  for (int i = 0; i < 4; ++i){
    int r = w * 64 + i * 16 + lrow;
    srcB[i] = Bk + (size_t)r * 512 + ((lpos ^ ((r >> 1) & 3)) * 8);
  }
  const u16* srcA = Aq;  // valid only for w<4
  {
    int r = (w & 3) * 16 + lrow;
    srcA = Aq + (size_t)(n0 + r) * 512 + ((lpos ^ ((r >> 1) & 3)) * 8);
  }
  char* ldsB = Bs + w * 4096;
  char* ldsA = As + (w & 3) * 1024;

  for (int kk = 0; kk < 16; ++kk){
    const int ko = kk * 32;
    __syncthreads();
    #pragma unroll
    for (int i = 0; i < 4; ++i)
      gload16(ldsB + i * 1024, srcB[i] + ko);
    if (w < 4) gload16(ldsA, srcA + ko);
    __syncthreads();
    bf16x8 af[4], bf[4];
    #pragma unroll
    for (int mi = 0; mi < 4; ++mi){
      int rr = mi * 16 + l15;
      af[mi] = *(const bf16x8*)(As + rr * 64 + ((l4 ^ ((rr >> 1) & 3)) * 16));
    }
    #pragma unroll
    for (int nj = 0; nj < 4; ++nj){
      int rb = w * 64 + nj * 16 + l15;
      bf[nj] = *(const bf16x8*)(Bs + rb * 64 + ((l4 ^ ((rb >> 1) & 3)) * 16));
    }
    #pragma unroll
    for (int mi = 0; mi < 4; ++mi)
      #pragma unroll
      for (int nj = 0; nj < 4; ++nj)
        acc[mi][nj] = __builtin_amdgcn_mfma_f32_16x16x32_bf16(af[mi], bf[nj], acc[mi][nj], 0, 0, 0);
  }

  // acc[mi][nj][e]: row = mi*16 + l4*4 + e (N), col = w*64 + nj*16 + l15 (slot).
  #pragma unroll
  for (int mi = 0; mi < 4; ++mi){
    #pragma unroll
    for (int e = 0; e < 4; ++e){
      const int row = mi * 16 + l4 * 4 + e;
      float m1 = -3e38f, m2 = -3e38f; int i1 = 0x7FFFFFFF, i2 = 0x7FFFFFFF;
      #pragma unroll
      for (int nj = 0; nj < 4; ++nj){
        float val = acc[mi][nj][e];
        int idx = w * 64 + nj * 16 + l15;
        if (val > m1){ m2 = m1; i2 = i1; m1 = val; i1 = idx; }
        else if (val > m2){ m2 = val; i2 = idx; }
      }
      #pragma unroll
      for (int d = 1; d < 16; d <<= 1){
        float o1 = __shfl_xor(m1, d), o2 = __shfl_xor(m2, d);
        int oi1 = __shfl_xor(i1, d), oi2 = __shfl_xor(i2, d);
        if (o1 > m1 || (o1 == m1 && oi1 < i1)){
          if (m1 > o2 || (m1 == o2 && i1 < oi2)){ m2 = m1; i2 = i1; }
          else { m2 = o2; i2 = oi2; }
          m1 = o1; i1 = oi1;
        } else {
          if (o1 > m2 || (o1 == m2 && oi1 < i2)){ m2 = o1; i2 = oi1; }
        }
      }
      if (l15 == 0){
        rs_m1[w][row] = m1; rs_i1[w][row] = i1;
        rs_m2[w][row] = m2; rs_i2[w][row] = i2;
      }
    }
  }
  #pragma unroll
  for (int nj = 0; nj < 4; ++nj){
    float cm = -3e38f;
    #pragma unroll
    for (int mi = 0; mi < 4; ++mi)
      #pragma unroll
      for (int e = 0; e < 4; ++e) cm = fmaxf(cm, acc[mi][nj][e]);
    cm = fmaxf(cm, __shfl_xor(cm, 16));
    cm = fmaxf(cm, __shfl_xor(cm, 32));
    if (l4 == 0) atomicMax(&colmax_u[w * 64 + nj * 16 + l15], fkey(cm));
  }
  #pragma unroll
  for (int mi = 0; mi < 4; ++mi)
    #pragma unroll
    for (int nj = 0; nj < 4; ++nj)
      #pragma unroll
      for (int e = 0; e < 4; ++e) acc[mi][nj][e] = expf(acc[mi][nj][e]);
  #pragma unroll
  for (int mi = 0; mi < 4; ++mi){
    #pragma unroll
    for (int e = 0; e < 4; ++e){
      const int row = mi * 16 + l4 * 4 + e;
      float ps = acc[mi][0][e] + acc[mi][1][e] + acc[mi][2][e] + acc[mi][3][e];
      #pragma unroll
      for (int d = 1; d < 16; d <<= 1) ps += __shfl_xor(ps, d);
      if (l15 == 0) rs_es[w][row] = ps;
    }
  }
  #pragma unroll
  for (int nj = 0; nj < 4; ++nj){
    float cs = 0.f;
    #pragma unroll
    for (int mi = 0; mi < 4; ++mi)
      #pragma unroll
      for (int e = 0; e < 4; ++e) cs += acc[mi][nj][e];
    cs += __shfl_xor(cs, 16);
    cs += __shfl_xor(cs, 32);
    if (l4 == 0) atomicAdd(&colsum[w * 64 + nj * 16 + l15], cs);
  }
  __syncthreads();
  if (t < 64){
    const int row = t, n = n0 + row;
    float m1 = -3e38f, m2 = -3e38f; int i1 = 0x7FFFFFFF, i2 = 0x7FFFFFFF;
    float tot = 0.f;
    #pragma unroll
    for (int w2 = 0; w2 < 8; ++w2){
      float o1 = rs_m1[w2][row], o2 = rs_m2[w2][row];
      int oi1 = rs_i1[w2][row], oi2 = rs_i2[w2][row];
      tot += rs_es[w2][row];
      if (o1 > m1 || (o1 == m1 && oi1 < i1)){
        if (m1 > o2 || (m1 == o2 && i1 < oi2)){ m2 = m1; i2 = i1; }
        else { m2 = o2; i2 = oi2; }
        m1 = o1; i1 = oi1;
      } else {
        if (o1 > m2 || (o1 == m2 && oi1 < i2)){ m2 = o1; i2 = oi1; }
      }
    }
    gidx[n] = i1; s1v[n] = m1; rfac[n] = tot;
    rtinv[row] = 1.0f / tot;
    float sq = sumq[n];
    float gl = 1.0f + kn2[i1] - 2.0f * m1;
    float dp2 = gl + 2e-6f * (sq - ksum[i1]) + 5.12e-10f;
    float dn2 = 1.0f + kn2[i2] - 2.0f * m2 + 2e-6f * (sq - ksum[i2]) + 5.12e-10f;
    float sl = fmaxf(sqrtf(dp2) - sqrtf(dn2) + 1.0f, 0.0f);
    #pragma unroll
    for (int d = 1; d < 64; d <<= 1){ gl += __shfl_xor(gl, d); sl += __shfl_xor(sl, d); }
    if (t == 0){ part[2 * blockIdx.x] = gl; part[2 * blockIdx.x + 1] = sl; }
  }
  __syncthreads();
  #pragma unroll
  for (int mi = 0; mi < 4; ++mi){
    #pragma unroll
    for (int e = 0; e < 4; ++e){
      const int row = mi * 16 + l4 * 4 + e;
      const float ri = rtinv[row];
      float* dst = SM + (size_t)(n0 + row) * 512 + w * 64 + l15;
      #pragma unroll
      for (int nj = 0; nj < 4; ++nj)
        dst[nj * 16] = acc[mi][nj][e] * ri;
    }
  }
}

// ---- K7: memory update. One block per slot j; wgt = exp(s1 - cm). Reads qb.
__global__ __launch_bounds__(256) void k7_update(const int* __restrict__ gidx,
    const float* __restrict__ s1v, const u32* __restrict__ colmax_u,
    const u16* __restrict__ qb, const float* __restrict__ keys, float* __restrict__ um)
{
  const int j = blockIdx.x;
  const int t = threadIdx.x;
  const int lane = t & 63;
  const int w = t >> 6;
  const float cm = fdec(colmax_u[j]);
  float acc[8] = {0.f, 0.f, 0.f, 0.f, 0.f, 0.f, 0.f, 0.f};
  const int b0 = w * 16384, b1 = b0 + 16384;
  for (int base = b0; base < b1; base += 64){
    u64 mask = __ballot(gidx[base + lane] == j);
    while (mask){
      int bpos = (int)__builtin_ctzll(mask);
      mask &= mask - 1;
      int rrow = base + bpos;
      float wgt = expf(s1v[rrow] - cm);
      uint4 rv = *(const uint4*)(qb + (size_t)rrow * 512 + lane * 8);
      u32 a4[4] = {rv.x, rv.y, rv.z, rv.w};
      #pragma unroll
      for (int q = 0; q < 4; ++q){
        acc[2 * q]     += wgt * bf2f((u16)(a4[q] & 0xFFFFu));
        acc[2 * q + 1] += wgt * bf2f((u16)(a4[q] >> 16));
      }
    }
  }
  __shared__ float red[512];
  for (int i = t; i < 512; i += 256) red[i] = 0.f;
  __syncthreads();
  #pragma unroll
  for (int k = 0; k < 8; ++k) atomicAdd(&red[lane * 8 + k], acc[k]);
  __syncthreads();
  float v0 = red[t]       + keys[(size_t)j * 512 + t];
  float v1 = red[t + 256] + keys[(size_t)j * 512 + t + 256];
  float ssq = v0 * v0 + v1 * v1;
  #pragma unroll
  for (int d = 1; d < 64; d <<= 1) ssq += __shfl_xor(ssq, d);
  __shared__ float rr4[4];
  if (lane == 0) rr4[w] = ssq;
  __syncthreads();
  const float rinv = 1.0f / fmaxf(sqrtf(rr4[0] + rr4[1] + rr4[2] + rr4[3]), 1e-12f);
  um[(size_t)j * 512 + t]       = v0 * rinv;
  um[(size_t)j * 512 + t + 256] = v1 * rinv;
}

// ---- K6f: concat GEMM + SQ side-write. 1024 blocks x 512 threads.
// A = kt (gload_lds staged, L2-resident), B = SM-tile f32->bf16 (register staged).
__global__ __launch_bounds__(512) void k6f(const float* __restrict__ SMf,
    const u16* __restrict__ kt, float* __restrict__ Uq, float* __restrict__ SQ,
    const float* __restrict__ rfac, const float* __restrict__ colsum)
{
  __shared__ __align__(16) char Ks[32768];   // 512 rows x 32 bf16
  __shared__ __align__(16) char Qs[4096];    // 64 rows x 32 bf16
  const int t = threadIdx.x;
  const int w = t >> 6;
  const int lane = t & 63;
  const int l15 = lane & 15, l4 = lane >> 4;
  const int n0 = blockIdx.x * 64;

  f32x4 acc[4][4];
  #pragma unroll
  for (int a = 0; a < 4; ++a)
    #pragma unroll
    for (int b = 0; b < 4; ++b) acc[a][b] = (f32x4){0.f, 0.f, 0.f, 0.f};

  // Ks staging sources (pre-swizzled), 4 chunks of 1024 B per wave
  const int lrow = lane >> 2;
  const int lpos = lane & 3;
  const u16* srcK[4];
  #pragma unroll
  for (int i = 0; i < 4; ++i){
    int r = w * 64 + i * 16 + lrow;
    srcK[i] = kt + (size_t)r * 512 + ((lpos ^ ((r >> 1) & 3)) * 8);
  }
  char* ldsK = Ks + w * 4096;
  // Qs register staging: thread -> (row rQ, 4 cols at c4)
  const int rQ = t >> 3;           // 0..63
  const int c4 = (t & 7) * 4;      // 0..28
  const size_t qrow = (size_t)(n0 + rQ) * 512;
  const float rf = rfac[n0 + rQ];
  const int qdst = rQ * 64 + (((c4 >> 3) ^ ((rQ >> 1) & 3)) * 16) + ((c4 & 4) << 1);

  float4 q0 = *(const float4*)(SMf + qrow + c4);

  for (int kk = 0; kk < 16; ++kk){
    const int ko = kk * 32;
    __syncthreads();
    *(u32*)(Qs + qdst)     = pack2(q0.x, q0.y);
    *(u32*)(Qs + qdst + 4) = pack2(q0.z, q0.w);
    #pragma unroll
    for (int i = 0; i < 4; ++i)
      gload16(ldsK + i * 1024, srcK[i] + ko);
    {
      float4 cs = *(const float4*)(colsum + ko + c4);
      float4 sq;
      sq.x = q0.x * rf / cs.x; sq.y = q0.y * rf / cs.y;
      sq.z = q0.z * rf / cs.z; sq.w = q0.w * rf / cs.w;
      *(float4*)(SQ + qrow + ko + c4) = sq;
    }
    __syncthreads();
    if (kk < 15) q0 = *(const float4*)(SMf + qrow + ko + 32 + c4);
    bf16x8 af[4], bf[4];
    #pragma unroll
    for (int mi = 0; mi < 4; ++mi){
      int rr = w * 64 + mi * 16 + l15;
      af[mi] = *(const bf16x8*)(Ks + rr * 64 + ((l4 ^ ((rr >> 1) & 3)) * 16));
    }
    #pragma unroll
    for (int nj = 0; nj < 4; ++nj){
      int rb = nj * 16 + l15;
      bf[nj] = *(const bf16x8*)(Qs + rb * 64 + ((l4 ^ ((rb >> 1) & 3)) * 16));
    }
    #pragma unroll
    for (int mi = 0; mi < 4; ++mi)
      #pragma unroll
      for (int nj = 0; nj < 4; ++nj)
        acc[mi][nj] = __builtin_amdgcn_mfma_f32_16x16x32_bf16(af[mi], bf[nj], acc[mi][nj], 0, 0, 0);
  }

  // C row = channel = w*64 + mi*16 + l4*4 + e ; col = pixel = nj*16 + l15.
  const int bq = n0 >> 10;
  const int p0 = n0 & 1023;
  #pragma unroll
  for (int mi = 0; mi < 4; ++mi){
    #pragma unroll
    for (int e = 0; e < 4; ++e){
      const int chn = w * 64 + mi * 16 + l4 * 4 + e;
      float* dst = Uq + (size_t)(bq * 1024 + 512 + chn) * 1024 + p0 + l15;
      #pragma unroll
      for (int nj = 0; nj < 4; ++nj)
        dst[nj * 16] = acc[mi][nj][e];
    }
  }
}

// ---- K9: reduce 1024 per-block loss partials -> scalar f32 outputs.
__global__ __launch_bounds__(256) void k9_fin(const float* __restrict__ part,
    float* __restrict__ outL)
{
  const int t = threadIdx.x;
  float gs = 0.f, ss = 0.f;
  for (int i = t; i < 1024; i += 256){ gs += part[2 * i]; ss += part[2 * i + 1]; }
  #pragma unroll
  for (int d = 1; d < 64; d <<= 1){ gs += __shfl_xor(gs, d); ss += __shfl_xor(ss, d); }
  __shared__ float rg[4], rs2[4];
  if ((t & 63) == 0){ rg[t >> 6] = gs; rs2[t >> 6] = ss; }
  __syncthreads();
  if (t == 0){
    float G = rg[0] + rg[1] + rg[2] + rg[3];
    float S = rs2[0] + rs2[1] + rs2[2] + rs2[3];
    outL[0] = G / (65536.0f * 512.0f);
    outL[1] = S / 65536.0f;
  }
}

extern "C" void kernel_launch(void* const* d_in, const int* in_sizes, int n_in,
                              void* d_out, int out_size, void* d_ws, size_t ws_size,
                              hipStream_t stream)
{
  int qi = 0, ki = 1;
  if (n_in >= 2 && in_sizes[0] < in_sizes[1]){ qi = 1; ki = 0; }
  const float* query = (const float*)d_in[qi];
  const float* keys  = (const float*)d_in[ki];
  float* out = (float*)d_out;

  // output offsets (f32 elements)
  const size_t OFF_UQ = 0;
  const size_t OFF_UM = 67108864;
  const size_t OFF_SQ = 67371008;
  const size_t OFF_SM = 100925440;
  const size_t OFF_GL = 134479872;

  // qb bf16 [N][512] parked in first half of the SQ region until K7; K6f overwrites.
  u16* qb = (u16*)(out + OFF_SQ);

  // workspace (~2.1 MB)
  char* ws = (char*)d_ws;
  u16*   kb     = (u16*)ws;                       //   524,288 B
  u16*   kt     = (u16*)(ws + 524288);            //   524,288
  float* sumq   = (float*)(ws + 1048576);         //   262,144
  int*   gidx   = (int*)(ws + 1310720);           //   262,144
  float* s1v    = (float*)(ws + 1572864);         //   262,144
  float* rfac   = (float*)(ws + 1835008);         //   262,144
  float* part   = (float*)(ws + 2097152);         //     8,192
  float* kn2    = (float*)(ws + 2105344);         //     2,048
  float* ksum   = (float*)(ws + 2107392);         //     2,048
  u32*   colmax = (u32*)(ws + 2109440);           //     2,048
  float* colsum = (float*)(ws + 2111488);         //     2,048

  k0_prep<<<512, 512, 0, stream>>>(keys, kb, kt, kn2, ksum, colmax, colsum);
  k1_norm<<<dim3(16, 64), 256, 0, stream>>>(query, out + OFF_UQ, qb, sumq);
  k2f<<<1024, 512, 0, stream>>>(qb, kb, out + OFF_SM, colmax, colsum,
                                gidx, s1v, rfac, kn2, ksum, sumq, part);
  k7_update<<<512, 256, 0, stream>>>(gidx, s1v, colmax, qb, keys, out + OFF_UM);
  k6f<<<1024, 512, 0, stream>>>(out + OFF_SM, kt, out + OFF_UQ, out + OFF_SQ,
                                rfac, colsum);
  k9_fin<<<1, 256, 0, stream>>>(part, out + OFF_GL);
}

// Round 9
// 375.978 us; speedup vs baseline: 1.7600x; 1.0228x over previous
//
#include <hip/hip_runtime.h>
#include <stdint.h>

// B=64, C=512, H=W=32 -> N=65536 pixels, m=512 slots, d=512 dims.
// Inputs f32: query (33,554,432 elems), keys (262,144) -- selected by size.
// Output f32 concat: updated_query [64][1024][32][32] | updated_memory [512][512]
//   | score_query [65536][512] | score_memory [65536][512] | g_loss | s_loss
//
// R9: R8 + double-buffered single-barrier K-steps in both GEMMs (T3 2-phase pattern:
// issue next-tile global_load_lds BEFORE current MFMA; one __syncthreads per step).
// K2f epilogue LDS overlays staging buffer 0. K7 widened to 512 threads.

typedef unsigned int u32;
typedef unsigned long long u64;
typedef unsigned short u16;

typedef float f32x4 __attribute__((ext_vector_type(4)));
typedef short bf16x8 __attribute__((ext_vector_type(8)));

#define DIMS 512

__device__ __forceinline__ u16 f2bf(float x){
  u32 u = __float_as_uint(x);
  return (u16)((u + 0x7FFFu + ((u >> 16) & 1u)) >> 16);
}
__device__ __forceinline__ float bf2f(u16 h){ return __uint_as_float(((u32)h) << 16); }
__device__ __forceinline__ u32 pack2(float a, float b){
  return (u32)f2bf(a) | ((u32)f2bf(b) << 16);
}
__device__ __forceinline__ u32 fkey(float x){
  u32 b = __float_as_uint(x);
  return (b & 0x80000000u) ? ~b : (b | 0x80000000u);
}
__device__ __forceinline__ float fdec(u32 u){
  return (u & 0x80000000u) ? __uint_as_float(u & 0x7FFFFFFFu) : __uint_as_float(~u);
}
// async global->LDS, 16 B per lane (wave-level: LDS dest = base + lane*16)
__device__ __forceinline__ void gload16(char* lds, const void* g){
  __builtin_amdgcn_global_load_lds(
      (const __attribute__((address_space(1))) u32*)g,
      (__attribute__((address_space(3))) u32*)lds, 16, 0, 0);
}

// ---- K0: keys prep. 512 blocks x 512 threads.
__global__ __launch_bounds__(512) void k0_prep(const float* __restrict__ keys,
    u16* __restrict__ kb, u16* __restrict__ kt,
    float* __restrict__ kn2, float* __restrict__ ksum,
    u32* __restrict__ colmax_u, float* __restrict__ colsum)
{
  const int j = blockIdx.x, t = threadIdx.x;
  float v = keys[(size_t)j * 512 + t];
  u16 h = f2bf(v);
  kb[(size_t)j * 512 + t] = h;
  kt[(size_t)t * 512 + j] = h;
  float s = v, ss = v * v;
  #pragma unroll
  for (int d = 1; d < 64; d <<= 1){ s += __shfl_xor(s, d); ss += __shfl_xor(ss, d); }
  __shared__ float rs[8], rss[8];
  const int w = t >> 6, lane = t & 63;
  if (lane == 0){ rs[w] = s; rss[w] = ss; }
  __syncthreads();
  if (t == 0){
    float S = 0.f, SS = 0.f;
    for (int i = 0; i < 8; ++i){ S += rs[i]; SS += rss[i]; }
    ksum[j] = S; kn2[j] = SS;
  }
  if (j == 0){ colmax_u[t] = 0u; colsum[t] = 0.f; }
}

// ---- K1: channel L2-normalize (single pass, 128 regs). q f32 -> UQ low; qb bf16
// row-major -> SQ region; per-pixel sum(q). grid (16,64), 256 threads.
__global__ __launch_bounds__(256) void k1_norm(const float* __restrict__ query,
    float* __restrict__ uq, u16* __restrict__ qb, float* __restrict__ sumq)
{
  __shared__ float red[4][64];
  __shared__ float rinvS[64];
  __shared__ float T[64][65];
  const int t = threadIdx.x;
  const int p = t & 63;
  const int cq = t >> 6;
  const int b = blockIdx.y;
  const int p0 = blockIdx.x * 64;
  const float* base = query + (size_t)b * 524288 + p0;

  float v[128];
  float ssq = 0.f;
  #pragma unroll
  for (int k = 0; k < 128; ++k){
    float x = base[(size_t)(cq + 4 * k) * 1024 + p];
    v[k] = x; ssq += x * x;
  }
  red[cq][p] = ssq;
  __syncthreads();
  if (t < 64){
    float tot = red[0][t] + red[1][t] + red[2][t] + red[3][t];
    rinvS[t] = 1.0f / fmaxf(sqrtf(tot), 1e-12f);
  }
  __syncthreads();
  const float rinv = rinvS[p];
  float* uqo = uq + (size_t)b * 1048576 + p0;
  float mysum = 0.f;
  const int r = t >> 2, seg = t & 3;
  for (int cb = 0; cb < 8; ++cb){
    #pragma unroll
    for (int i = 0; i < 16; ++i){
      int c = cb * 64 + cq + i * 4;
      float x = v[cb * 16 + i] * rinv;
      uqo[(size_t)c * 1024 + p] = x;
      T[cq + i * 4][p] = x;
      mysum += x;
    }
    __syncthreads();
    {
      u32 wpk[8];
      #pragma unroll
      for (int k = 0; k < 8; ++k)
        wpk[k] = pack2(T[seg * 16 + 2 * k][r], T[seg * 16 + 2 * k + 1][r]);
      uint4* dst = (uint4*)(qb + ((size_t)(b * 1024 + p0 + r)) * 512 + cb * 64 + seg * 16);
      dst[0] = make_uint4(wpk[0], wpk[1], wpk[2], wpk[3]);
      dst[1] = make_uint4(wpk[4], wpk[5], wpk[6], wpk[7]);
    }
    __syncthreads();
  }
  red[cq][p] = mysum;
  __syncthreads();
  if (t < 64)
    sumq[(size_t)b * 1024 + p0 + t] = red[0][t] + red[1][t] + red[2][t] + red[3][t];
}

// ---- K2f: fused score GEMM + row stats + SM + col atomics + losses.
// 1024 blocks x 512 threads (8 waves). 64 N-rows x all 512 slots, BK=32,
// double-buffered LDS, ONE barrier per K-step. Epilogue arrays overlay buffer 0.
__global__ __launch_bounds__(512) void k2f(const u16* __restrict__ Aq,
    const u16* __restrict__ Bk, float* __restrict__ SM,
    u32* __restrict__ colmax_u, float* __restrict__ colsum,
    int* __restrict__ gidx, float* __restrict__ s1v, float* __restrict__ rfac,
    const float* __restrict__ kn2, const float* __restrict__ ksum,
    const float* __restrict__ sumq, float* __restrict__ part)
{
  // layout: As0 @0 (4K), As1 @4096, Bs0 @8192 (32K), Bs1 @40960 (32K)  = 72 KB
  __shared__ __align__(16) char smem[73728];
  const int t = threadIdx.x;
  const int w = t >> 6;
  const int lane = t & 63;
  const int l15 = lane & 15, l4 = lane >> 4;
  const int n0 = blockIdx.x * 64;

  f32x4 acc[4][4];
  #pragma unroll
  for (int a = 0; a < 4; ++a)
    #pragma unroll
    for (int b = 0; b < 4; ++b) acc[a][b] = (f32x4){0.f, 0.f, 0.f, 0.f};

  // per-lane staging sources (pre-swizzled): chunk = 1024 B = 16 rows
  const int lrow = lane >> 2;
  const int lpos = lane & 3;
  const u16* srcB[4];
  #pragma unroll
  for (int i = 0; i < 4; ++i){
    int r = w * 64 + i * 16 + lrow;
    srcB[i] = Bk + (size_t)r * 512 + ((lpos ^ ((r >> 1) & 3)) * 8);
  }
  const u16* srcA;
  {
    int r = (w & 3) * 16 + lrow;
    srcA = Aq + (size_t)(n0 + r) * 512 + ((lpos ^ ((r >> 1) & 3)) * 8);
  }

  // prologue: stage tile 0 -> buf0
  {
    char* ldsB = smem + 8192 + w * 4096;
    #pragma unroll
    for (int i = 0; i < 4; ++i) gload16(ldsB + i * 1024, srcB[i]);
    if (w < 4) gload16(smem + (w & 3) * 1024, srcA);
  }
  __syncthreads();

  for (int kk = 0; kk < 16; ++kk){
    const int cur = kk & 1;
    if (kk < 15){
      const int nxt = cur ^ 1;
      const int ko = (kk + 1) * 32;
      char* ldsB = smem + 8192 + nxt * 32768 + w * 4096;
      #pragma unroll
      for (int i = 0; i < 4; ++i) gload16(ldsB + i * 1024, srcB[i] + ko);
      if (w < 4) gload16(smem + nxt * 4096 + (w & 3) * 1024, srcA + ko);
    }
    const char* As = smem + cur * 4096;
    const char* Bs = smem + 8192 + cur * 32768;
    bf16x8 af[4], bf[4];
    #pragma unroll
    for (int mi = 0; mi < 4; ++mi){
      int rr = mi * 16 + l15;
      af[mi] = *(const bf16x8*)(As + rr * 64 + ((l4 ^ ((rr >> 1) & 3)) * 16));
    }
    #pragma unroll
    for (int nj = 0; nj < 4; ++nj){
      int rb = w * 64 + nj * 16 + l15;
      bf[nj] = *(const bf16x8*)(Bs + rb * 64 + ((l4 ^ ((rb >> 1) & 3)) * 16));
    }
    #pragma unroll
    for (int mi = 0; mi < 4; ++mi)
      #pragma unroll
      for (int nj = 0; nj < 4; ++nj)
        acc[mi][nj] = __builtin_amdgcn_mfma_f32_16x16x32_bf16(af[mi], bf[nj], acc[mi][nj], 0, 0, 0);
    __syncthreads();
  }

  // epilogue LDS overlays buffer-0 region (dead: last K-step read buf1)
  float* rs_m1 = (float*)(smem + 8192);     // [8][64]
  float* rs_m2 = (float*)(smem + 10240);
  float* rs_es = (float*)(smem + 12288);
  int*   rs_i1 = (int*)(smem + 14336);
  int*   rs_i2 = (int*)(smem + 16384);
  float* rtinv = (float*)(smem + 18432);    // [64]

  // acc[mi][nj][e]: row = mi*16 + l4*4 + e (N), col = w*64 + nj*16 + l15 (slot).
  #pragma unroll
  for (int mi = 0; mi < 4; ++mi){
    #pragma unroll
    for (int e = 0; e < 4; ++e){
      const int row = mi * 16 + l4 * 4 + e;
      float m1 = -3e38f, m2 = -3e38f; int i1 = 0x7FFFFFFF, i2 = 0x7FFFFFFF;
      #pragma unroll
      for (int nj = 0; nj < 4; ++nj){
        float val = acc[mi][nj][e];
        int idx = w * 64 + nj * 16 + l15;
        if (val > m1){ m2 = m1; i2 = i1; m1 = val; i1 = idx; }
        else if (val > m2){ m2 = val; i2 = idx; }
      }
      #pragma unroll
      for (int d = 1; d < 16; d <<= 1){
        float o1 = __shfl_xor(m1, d), o2 = __shfl_xor(m2, d);
        int oi1 = __shfl_xor(i1, d), oi2 = __shfl_xor(i2, d);
        if (o1 > m1 || (o1 == m1 && oi1 < i1)){
          if (m1 > o2 || (m1 == o2 && i1 < oi2)){ m2 = m1; i2 = i1; }
          else { m2 = o2; i2 = oi2; }
          m1 = o1; i1 = oi1;
        } else {
          if (o1 > m2 || (o1 == m2 && oi1 < i2)){ m2 = o1; i2 = oi1; }
        }
      }
      if (l15 == 0){
        rs_m1[w * 64 + row] = m1; rs_i1[w * 64 + row] = i1;
        rs_m2[w * 64 + row] = m2; rs_i2[w * 64 + row] = i2;
      }
    }
  }
  #pragma unroll
  for (int nj = 0; nj < 4; ++nj){
    float cm = -3e38f;
    #pragma unroll
    for (int mi = 0; mi < 4; ++mi)
      #pragma unroll
      for (int e = 0; e < 4; ++e) cm = fmaxf(cm, acc[mi][nj][e]);
    cm = fmaxf(cm, __shfl_xor(cm, 16));
    cm = fmaxf(cm, __shfl_xor(cm, 32));
    if (l4 == 0) atomicMax(&colmax_u[w * 64 + nj * 16 + l15], fkey(cm));
  }
  #pragma unroll
  for (int mi = 0; mi < 4; ++mi)
    #pragma unroll
    for (int nj = 0; nj < 4; ++nj)
      #pragma unroll
      for (int e = 0; e < 4; ++e) acc[mi][nj][e] = expf(acc[mi][nj][e]);
  #pragma unroll
  for (int mi = 0; mi < 4; ++mi){
    #pragma unroll
    for (int e = 0; e < 4; ++e){
      const int row = mi * 16 + l4 * 4 + e;
      float ps = acc[mi][0][e] + acc[mi][1][e] + acc[mi][2][e] + acc[mi][3][e];
      #pragma unroll
      for (int d = 1; d < 16; d <<= 1) ps += __shfl_xor(ps, d);
      if (l15 == 0) rs_es[w * 64 + row] = ps;
    }
  }
  #pragma unroll
  for (int nj = 0; nj < 4; ++nj){
    float cs = 0.f;
    #pragma unroll
    for (int mi = 0; mi < 4; ++mi)
      #pragma unroll
      for (int e = 0; e < 4; ++e) cs += acc[mi][nj][e];
    cs += __shfl_xor(cs, 16);
    cs += __shfl_xor(cs, 32);
    if (l4 == 0) atomicAdd(&colsum[w * 64 + nj * 16 + l15], cs);
  }
  __syncthreads();
  if (t < 64){
    const int row = t, n = n0 + row;
    float m1 = -3e38f, m2 = -3e38f; int i1 = 0x7FFFFFFF, i2 = 0x7FFFFFFF;
    float tot = 0.f;
    #pragma unroll
    for (int w2 = 0; w2 < 8; ++w2){
      float o1 = rs_m1[w2 * 64 + row], o2 = rs_m2[w2 * 64 + row];
      int oi1 = rs_i1[w2 * 64 + row], oi2 = rs_i2[w2 * 64 + row];
      tot += rs_es[w2 * 64 + row];
      if (o1 > m1 || (o1 == m1 && oi1 < i1)){
        if (m1 > o2 || (m1 == o2 && i1 < oi2)){ m2 = m1; i2 = i1; }
        else { m2 = o2; i2 = oi2; }
        m1 = o1; i1 = oi1;
      } else {
        if (o1 > m2 || (o1 == m2 && oi1 < i2)){ m2 = o1; i2 = oi1; }
      }
    }
    gidx[n] = i1; s1v[n] = m1; rfac[n] = tot;
    rtinv[row] = 1.0f / tot;
    float sq = sumq[n];
    float gl = 1.0f + kn2[i1] - 2.0f * m1;
    float dp2 = gl + 2e-6f * (sq - ksum[i1]) + 5.12e-10f;
    float dn2 = 1.0f + kn2[i2] - 2.0f * m2 + 2e-6f * (sq - ksum[i2]) + 5.12e-10f;
    float sl = fmaxf(sqrtf(dp2) - sqrtf(dn2) + 1.0f, 0.0f);
    #pragma unroll
    for (int d = 1; d < 64; d <<= 1){ gl += __shfl_xor(gl, d); sl += __shfl_xor(sl, d); }
    if (t == 0){ part[2 * blockIdx.x] = gl; part[2 * blockIdx.x + 1] = sl; }
  }
  __syncthreads();
  #pragma unroll
  for (int mi = 0; mi < 4; ++mi){
    #pragma unroll
    for (int e = 0; e < 4; ++e){
      const int row = mi * 16 + l4 * 4 + e;
      const float ri = rtinv[row];
      float* dst = SM + (size_t)(n0 + row) * 512 + w * 64 + l15;
      #pragma unroll
      for (int nj = 0; nj < 4; ++nj)
        dst[nj * 16] = acc[mi][nj][e] * ri;
    }
  }
}

// ---- K7: memory update, 512 threads (8 waves x 8192 rows). wgt = exp(s1 - cm).
__global__ __launch_bounds__(512) void k7_update(const int* __restrict__ gidx,
    const float* __restrict__ s1v, const u32* __restrict__ colmax_u,
    const u16* __restrict__ qb, const float* __restrict__ keys, float* __restrict__ um)
{
  const int j = blockIdx.x;
  const int t = threadIdx.x;
  const int lane = t & 63;
  const int w = t >> 6;
  const float cm = fdec(colmax_u[j]);
  float acc[8] = {0.f, 0.f, 0.f, 0.f, 0.f, 0.f, 0.f, 0.f};
  const int b0 = w * 8192, b1 = b0 + 8192;
  for (int base = b0; base < b1; base += 64){
    u64 mask = __ballot(gidx[base + lane] == j);
    while (mask){
      int bpos = (int)__builtin_ctzll(mask);
      mask &= mask - 1;
      int rrow = base + bpos;
      float wgt = expf(s1v[rrow] - cm);
      uint4 rv = *(const uint4*)(qb + (size_t)rrow * 512 + lane * 8);
      u32 a4[4] = {rv.x, rv.y, rv.z, rv.w};
      #pragma unroll
      for (int q = 0; q < 4; ++q){
        acc[2 * q]     += wgt * bf2f((u16)(a4[q] & 0xFFFFu));
        acc[2 * q + 1] += wgt * bf2f((u16)(a4[q] >> 16));
      }
    }
  }
  __shared__ float red[512];
  red[t] = 0.f;
  __syncthreads();
  #pragma unroll
  for (int k = 0; k < 8; ++k) atomicAdd(&red[lane * 8 + k], acc[k]);
  __syncthreads();
  float v0 = red[t] + keys[(size_t)j * 512 + t];
  float ssq = v0 * v0;
  #pragma unroll
  for (int d = 1; d < 64; d <<= 1) ssq += __shfl_xor(ssq, d);
  __shared__ float rr8[8];
  if (lane == 0) rr8[w] = ssq;
  __syncthreads();
  float tot = rr8[0] + rr8[1] + rr8[2] + rr8[3] + rr8[4] + rr8[5] + rr8[6] + rr8[7];
  const float rinv = 1.0f / fmaxf(sqrtf(tot), 1e-12f);
  um[(size_t)j * 512 + t] = v0 * rinv;
}

// ---- K6f: concat GEMM + SQ side-write. 1024 blocks x 512 threads, double-buffered,
// one barrier per K-step. A = kt (gload_lds), B = SM f32->bf16 (depth-2 reg pipeline).
__global__ __launch_bounds__(512) void k6f(const float* __restrict__ SMf,
    const u16* __restrict__ kt, float* __restrict__ Uq, float* __restrict__ SQ,
    const float* __restrict__ rfac, const float* __restrict__ colsum)
{
  // Ks0 @0 (32K), Ks1 @32768, Qs0 @65536 (4K), Qs1 @69632  = 72 KB
  __shared__ __align__(16) char smem[73728];
  const int t = threadIdx.x;
  const int w = t >> 6;
  const int lane = t & 63;
  const int l15 = lane & 15, l4 = lane >> 4;
  const int n0 = blockIdx.x * 64;

  f32x4 acc[4][4];
  #pragma unroll
  for (int a = 0; a < 4; ++a)
    #pragma unroll
    for (int b = 0; b < 4; ++b) acc[a][b] = (f32x4){0.f, 0.f, 0.f, 0.f};

  const int lrow = lane >> 2;
  const int lpos = lane & 3;
  const u16* srcK[4];
  #pragma unroll
  for (int i = 0; i < 4; ++i){
    int r = w * 64 + i * 16 + lrow;
    srcK[i] = kt + (size_t)r * 512 + ((lpos ^ ((r >> 1) & 3)) * 8);
  }
  const int rQ = t >> 3;           // 0..63
  const int c4 = (t & 7) * 4;      // 0..28
  const size_t qrow = (size_t)(n0 + rQ) * 512;
  const float rf = rfac[n0 + rQ];
  const int qdst = rQ * 64 + (((c4 >> 3) ^ ((rQ >> 1) & 3)) * 16) + ((c4 & 4) << 1);

  // prologue: tile 0 staged to buf0; q pipeline depth 2
  float4 qcur = *(const float4*)(SMf + qrow + c4);
  {
    char* Qs0 = smem + 65536;
    *(u32*)(Qs0 + qdst)     = pack2(qcur.x, qcur.y);
    *(u32*)(Qs0 + qdst + 4) = pack2(qcur.z, qcur.w);
    float4 cs = *(const float4*)(colsum + c4);
    float4 sq;
    sq.x = qcur.x * rf / cs.x; sq.y = qcur.y * rf / cs.y;
    sq.z = qcur.z * rf / cs.z; sq.w = qcur.w * rf / cs.w;
    *(float4*)(SQ + qrow + c4) = sq;
    char* ldsK = smem + w * 4096;
    #pragma unroll
    for (int i = 0; i < 4; ++i) gload16(ldsK + i * 1024, srcK[i]);
  }
  float4 qnext = *(const float4*)(SMf + qrow + 32 + c4);
  __syncthreads();

  for (int kk = 0; kk < 16; ++kk){
    const int cur = kk & 1;
    if (kk < 15){
      const int nxt = cur ^ 1;
      const int ko = (kk + 1) * 32;
      char* ldsK = smem + nxt * 32768 + w * 4096;
      #pragma unroll
      for (int i = 0; i < 4; ++i) gload16(ldsK + i * 1024, srcK[i] + ko);
      char* QsN = smem + 65536 + nxt * 4096;
      *(u32*)(QsN + qdst)     = pack2(qnext.x, qnext.y);
      *(u32*)(QsN + qdst + 4) = pack2(qnext.z, qnext.w);
      float4 cs = *(const float4*)(colsum + ko + c4);
      float4 sq;
      sq.x = qnext.x * rf / cs.x; sq.y = qnext.y * rf / cs.y;
      sq.z = qnext.z * rf / cs.z; sq.w = qnext.w * rf / cs.w;
      *(float4*)(SQ + qrow + ko + c4) = sq;
      if (kk < 14) qnext = *(const float4*)(SMf + qrow + ko + 32 + c4);
    }
    const char* Ks = smem + cur * 32768;
    const char* Qs = smem + 65536 + cur * 4096;
    bf16x8 af[4], bf[4];
    #pragma unroll
    for (int mi = 0; mi < 4; ++mi){
      int rr = w * 64 + mi * 16 + l15;
      af[mi] = *(const bf16x8*)(Ks + rr * 64 + ((l4 ^ ((rr >> 1) & 3)) * 16));
    }
    #pragma unroll
    for (int nj = 0; nj < 4; ++nj){
      int rb = nj * 16 + l15;
      bf[nj] = *(const bf16x8*)(Qs + rb * 64 + ((l4 ^ ((rb >> 1) & 3)) * 16));
    }
    #pragma unroll
    for (int mi = 0; mi < 4; ++mi)
      #pragma unroll
      for (int nj = 0; nj < 4; ++nj)
        acc[mi][nj] = __builtin_amdgcn_mfma_f32_16x16x32_bf16(af[mi], bf[nj], acc[mi][nj], 0, 0, 0);
    __syncthreads();
  }

  // C row = channel = w*64 + mi*16 + l4*4 + e ; col = pixel = nj*16 + l15.
  const int bq = n0 >> 10;
  const int p0 = n0 & 1023;
  #pragma unroll
  for (int mi = 0; mi < 4; ++mi){
    #pragma unroll
    for (int e = 0; e < 4; ++e){
      const int chn = w * 64 + mi * 16 + l4 * 4 + e;
      float* dst = Uq + (size_t)(bq * 1024 + 512 + chn) * 1024 + p0 + l15;
      #pragma unroll
      for (int nj = 0; nj < 4; ++nj)
        dst[nj * 16] = acc[mi][nj][e];
    }
  }
}

// ---- K9: reduce 1024 per-block loss partials -> scalar f32 outputs.
__global__ __launch_bounds__(256) void k9_fin(const float* __restrict__ part,
    float* __restrict__ outL)
{
  const int t = threadIdx.x;
  float gs = 0.f, ss = 0.f;
  for (int i = t; i < 1024; i += 256){ gs += part[2 * i]; ss += part[2 * i + 1]; }
  #pragma unroll
  for (int d = 1; d < 64; d <<= 1){ gs += __shfl_xor(gs, d); ss += __shfl_xor(ss, d); }
  __shared__ float rg[4], rs2[4];
  if ((t & 63) == 0){ rg[t >> 6] = gs; rs2[t >> 6] = ss; }
  __syncthreads();
  if (t == 0){
    float G = rg[0] + rg[1] + rg[2] + rg[3];
    float S = rs2[0] + rs2[1] + rs2[2] + rs2[3];
    outL[0] = G / (65536.0f * 512.0f);
    outL[1] = S / 65536.0f;
  }
}

extern "C" void kernel_launch(void* const* d_in, const int* in_sizes, int n_in,
                              void* d_out, int out_size, void* d_ws, size_t ws_size,
                              hipStream_t stream)
{
  int qi = 0, ki = 1;
  if (n_in >= 2 && in_sizes[0] < in_sizes[1]){ qi = 1; ki = 0; }
  const float* query = (const float*)d_in[qi];
  const float* keys  = (const float*)d_in[ki];
  float* out = (float*)d_out;

  // output offsets (f32 elements)
  const size_t OFF_UQ = 0;
  const size_t OFF_UM = 67108864;
  const size_t OFF_SQ = 67371008;
  const size_t OFF_SM = 100925440;
  const size_t OFF_GL = 134479872;

  // qb bf16 [N][512] parked in first half of the SQ region until K7; K6f overwrites.
  u16* qb = (u16*)(out + OFF_SQ);

  // workspace (~2.1 MB)
  char* ws = (char*)d_ws;
  u16*   kb     = (u16*)ws;                       //   524,288 B
  u16*   kt     = (u16*)(ws + 524288);            //   524,288
  float* sumq   = (float*)(ws + 1048576);         //   262,144
  int*   gidx   = (int*)(ws + 1310720);           //   262,144
  float* s1v    = (float*)(ws + 1572864);         //   262,144
  float* rfac   = (float*)(ws + 1835008);         //   262,144
  float* part   = (float*)(ws + 2097152);         //     8,192
  float* kn2    = (float*)(ws + 2105344);         //     2,048
  float* ksum   = (float*)(ws + 2107392);         //     2,048
  u32*   colmax = (u32*)(ws + 2109440);           //     2,048
  float* colsum = (float*)(ws + 2111488);         //     2,048

  k0_prep<<<512, 512, 0, stream>>>(keys, kb, kt, kn2, ksum, colmax, colsum);
  k1_norm<<<dim3(16, 64), 256, 0, stream>>>(query, out + OFF_UQ, qb, sumq);
  k2f<<<1024, 512, 0, stream>>>(qb, kb, out + OFF_SM, colmax, colsum,
                                gidx, s1v, rfac, kn2, ksum, sumq, part);
  k7_update<<<512, 512, 0, stream>>>(gidx, s1v, colmax, qb, keys, out + OFF_UM);
  k6f<<<1024, 512, 0, stream>>>(out + OFF_SM, kt, out + OFF_UQ, out + OFF_SQ,
                                rfac, colsum);
  k9_fin<<<1, 256, 0, stream>>>(part, out + OFF_GL);
}